// Round 4
// baseline (705.861 us; speedup 1.0000x reference)
//
#include <hip/hip_runtime.h>
#include <hip/hip_fp16.h>
#include <hip/hip_cooperative_groups.h>
#include <cstdint>

namespace cg = cooperative_groups;

// Problem constants (setup_inputs: B=8, H=W=512, num_erosions=2)
static constexpr int B = 8;
static constexpr int H = 512;
static constexpr int W = 512;
static constexpr int HW = H * W;
static constexpr int NPIX = B * HW;
static constexpr int NB1 = 1024;  // blocks for erosion coop kernel / partials
static constexpr int NBD = 1024;  // legacy partial stride (finalize layout)

// cp_main tiling: interior = 16x32 tiles (2 px/thread), edge ring = 16x16
static constexpr int N_INT = 30 * 14;   // txB in [1,30], tyB in [1,14]
static constexpr int N_EDGE = 64 + 120; // 2 cols x 32 + 4 rows x 30
static constexpr int GRID_X = N_INT + N_EDGE;  // 604

// 10*log2(e): sigmoid(10*z) = 1/(1+2^(-CC*z))
static constexpr float CC = 14.4269504088896f;

// ---------------- helpers ----------------------------------------------------
// R14: interleaved CP records (WRITE 419->49MB). R15: f2 (P,G) VOP3P packing.
// R16: 2px/thread interior + hoisted consts -> 164us, VALUBusy 82% (issue
//   envelope; trans 62exp+124rcp/output irreducible — product-rcp trick
//   rejected: w*s=2^(CC(nc-1)) overflows f32, fused form NaNs where the
//   separate rcp(inf)=0 is benign).
// R17: (1) erosion chain (2 cross_max + 2 erode + setup) fused into ONE
//   cooperative kernel, 4 grid.sync, 1024 co-resident blocks (4/CU) — kills
//   4 launch gaps + drain tails. (2) dil_diff: 2 cols/thread, 3-row ring
//   (4 loads/row for 2 outputs vs 6; VGPR ~50). (3) cp fill loops: div/mod
//   -> strength-reduced increments (bit-identical).
__device__ __forceinline__ float rcpf(float x) { return __builtin_amdgcn_rcpf(x); }
__device__ __forceinline__ float exp2f_n(float x) { return __builtin_amdgcn_exp2f(x); }

typedef __attribute__((ext_vector_type(2))) float f2;

__device__ __forceinline__ f2 mk2(float a, float b) { f2 r; r.x = a; r.y = b; return r; }
__device__ __forceinline__ f2 exp2_2(f2 v) {
    f2 r; r.x = exp2f_n(v.x); r.y = exp2f_n(v.y); return r;
}
__device__ __forceinline__ f2 rcp_2(f2 v) {
    f2 r; r.x = rcpf(v.x); r.y = rcpf(v.y); return r;
}
#if defined(__has_builtin)
#if __has_builtin(__builtin_elementwise_fma)
#define FMA2(a, b, c) __builtin_elementwise_fma((a), (b), (c))
#endif
#endif
#ifndef FMA2
__device__ __forceinline__ f2 fma2_(f2 a, f2 b, f2 c) {
    f2 r; r.x = fmaf(a.x, b.x, c.x); r.y = fmaf(a.y, b.y, c.y); return r;
}
#define FMA2(a, b, c) fma2_((a), (b), (c))
#endif

__device__ __forceinline__ float sig_cp(float x) {  // sigmoid(10(x-0.5))
    return rcpf(1.0f + exp2f_n(fmaf(x, -CC, 0.5f * CC)));
}
__device__ __forceinline__ float sig_er(float r) {  // sigmoid(10(r-0.7))
    return rcpf(1.0f + exp2f_n(fmaf(r, -CC, 0.7f * CC)));
}
// Shared-exp complement pair (R12): one exp per (direct, complement) pair.
__device__ __forceinline__ void pair_term2(f2 nc, f2 negA, f2 s2m,
                                           f2& sd, f2& sc) {
    const f2 CC2 = CC;
    const f2 one2 = 1.0f;
    f2 w = exp2_2(FMA2(nc, CC2, negA));
    sd += rcp_2(FMA2(w, s2m, one2));
    sc += w * rcp_2(w + s2m);
}
// plain direct-only sigmoid (padded edge phases), f2 lanes (P, G)
__device__ __forceinline__ void end_term2(f2 nc, f2& sd) {
    const f2 CC2 = CC;
    const f2 nCC2 = -CC;
    const f2 one2 = 1.0f;
    sd += rcp_2(one2 + exp2_2(FMA2(nc, CC2, nCC2)));
}
__device__ __forceinline__ float wave_max(float m) {
#pragma unroll
    for (int o = 32; o > 0; o >>= 1) m = fmaxf(m, __shfl_down(m, o, 64));
    return m;
}
__device__ __forceinline__ float wave_sum(float s) {
#pragma unroll
    for (int o = 32; o > 0; o >>= 1) s += __shfl_down(s, o, 64);
    return s;
}

// packed 4x f16 pixel record (planes interleaved)
union H4 {
    uint64_t u;
    __half2 h2[2];
    __half h[4];
};

__device__ __forceinline__ float4 h4_to_f4(uint64_t u) {
    H4 v; v.u = u;
    float2 p0 = __half22float2(v.h2[0]);
    float2 p1 = __half22float2(v.h2[1]);
    return make_float4(p0.x, p0.y, p1.x, p1.y);
}
__device__ __forceinline__ float4 f4_add(float4 a, float4 b) {
    return make_float4(a.x + b.x, a.y + b.y, a.z + b.z, a.w + b.w);
}

// ---------------- row-sweep mask conv sums (f2: lanes = P,G) -----------------
struct NC2 {
    f2 n3[8], n4[8], n5[8], n6[7];
    f2 v;  // center value w[3][3]
};

template <int STRIDE>
__device__ __forceinline__ NC2 sweep2(const f2* rp) {
    NC2 o;
    f2 r2s, r3s, r4s;
    f2 cen0, cen1, cen2, cen3, cen4, cen5, cen6, cen7, cen8;
    {   // win row 0 = K6 row 0
        f2 c0 = rp[0], c1 = rp[1], c2 = rp[2], c3 = rp[3], c4 = rp[4], c5 = rp[5];
        f2 c45 = c4 + c5, c01 = c0 + c1;
        f2 S6 = (c01 + (c2 + c3)) + c45;
        o.n6[0] = c45; o.n6[1] = c01; o.n6[2] = S6; o.n6[3] = S6;
        o.n6[4] = S6;  o.n6[5] = S6;  o.n6[6] = S6;
    }
    rp += STRIDE;
    {   // win row 1 = K6 r1, K5 r0, K4 r0
        f2 c0 = rp[0], c1 = rp[1], c2 = rp[2], c3 = rp[3], c4 = rp[4], c5 = rp[5];
        f2 c45 = c4 + c5, c12 = c1 + c2, c34 = c3 + c4;
        f2 S4 = c12 + c34, S5 = S4 + c5;
        f2 c15 = c1 + c5, c05 = c0 + c5, c14 = c1 + c4;
        o.n6[0] += c5;  o.n6[1] += c0;  o.n6[2] += c05; o.n6[3] += c05;
        o.n6[4] += c0;  o.n6[5] += c5;  o.n6[6] += c05;
        o.n5[0] = c45; o.n5[1] = c12; o.n5[2] = S5; o.n5[3] = S5;
        o.n5[4] = S5;  o.n5[5] = S5;  o.n5[6] = S5; o.n5[7] = c15;
        o.n4[0] = c34; o.n4[1] = c12; o.n4[2] = S4; o.n4[3] = S4;
        o.n4[4] = c14; o.n4[5] = S4;  o.n4[6] = S4; o.n4[7] = S4;
    }
    rp += STRIDE;
    {   // win row 2 = K6 r2, K5 r1, K4 r1, K3 r0
        f2 c0 = rp[0], c1 = rp[1], c2 = rp[2], c3 = rp[3], c4 = rp[4], c5 = rp[5];
        f2 c05 = c0 + c5, c15 = c1 + c5, c14 = c1 + c4;
        r2s = (c2 + c3) + c4;
        cen0 = c2; cen1 = c3; cen2 = c4;
        o.n6[0] += c5;  o.n6[1] += c0;  o.n6[2] += c0;  o.n6[3] += c5;
        o.n6[4] += c0;  o.n6[5] += c5;  o.n6[6] += c05;
        o.n5[0] += c5;  o.n5[1] += c1;  o.n5[2] += c15; o.n5[3] += c15;
        o.n5[4] += c1;  o.n5[5] += c5;  o.n5[6] += c15; o.n5[7] += c15;
        o.n4[0] += c4;  o.n4[1] += c1;  o.n4[2] += c14; o.n4[3] += c14;
        o.n4[4] += c14; o.n4[5] += c4;  o.n4[6] += c14; o.n4[7] += c1;
    }
    rp += STRIDE;
    {   // win row 3 = K6 r3, K5 r2, K4 r2, K3 r1 (center row)
        f2 c0 = rp[0], c1 = rp[1], c2 = rp[2], c3 = rp[3], c4 = rp[4], c5 = rp[5];
        f2 c05 = c0 + c5, c15 = c1 + c5, c14 = c1 + c4;
        r3s = (c2 + c3) + c4;
        cen3 = c2; cen4 = c3; cen5 = c4;
        o.v = c3;
        o.n6[0] += c5;  o.n6[1] += c0;  o.n6[2] += c0;  o.n6[3] += c5;
        o.n6[4] += c0;  o.n6[5] += c5;  o.n6[6] += c05;
        o.n5[0] += c5;  o.n5[1] += c1;  o.n5[2] += c1;  o.n5[3] += c5;
        o.n5[4] += c1;  o.n5[5] += c5;  o.n5[6] += c15; o.n5[7] += c15;
        o.n4[0] += c14; o.n4[1] += c14; o.n4[2] += c4;  o.n4[3] += c1;
        o.n4[4] += c14; o.n4[5] += c4;  o.n4[6] += c14; o.n4[7] += c1;
    }
    rp += STRIDE;
    {   // win row 4 = K6 r4, K5 r3, K4 r3, K3 r2
        f2 c0 = rp[0], c1 = rp[1], c2 = rp[2], c3 = rp[3], c4 = rp[4], c5 = rp[5];
        f2 c05 = c0 + c5, c15 = c1 + c5, c12 = c1 + c2, c34 = c3 + c4;
        f2 S4 = c12 + c34, c14 = c1 + c4;
        r4s = (c2 + c3) + c4;
        cen6 = c2; cen7 = c3; cen8 = c4;
        o.n6[0] += c05; o.n6[1] += c05; o.n6[2] += c0;  o.n6[3] += c5;
        o.n6[4] += c0;  o.n6[5] += c5;  o.n6[6] += c05;
        o.n5[0] += c15; o.n5[1] += c15; o.n5[2] += c1;  o.n5[3] += c5;
        o.n5[4] += c1;  o.n5[5] += c5;  o.n5[6] += c15; o.n5[7] += c15;
        o.n4[0] += S4;  o.n4[1] += S4;  o.n4[2] += c34; o.n4[3] += c12;
        o.n4[4] += S4;  o.n4[5] += S4;  o.n4[6] += c14; o.n4[7] += S4;
    }
    rp += STRIDE;
    {   // win row 5 = K6 r5, K5 r4
        f2 c0 = rp[0], c1 = rp[1], c2 = rp[2], c3 = rp[3], c4 = rp[4], c5 = rp[5];
        f2 c45 = c4 + c5, c12 = c1 + c2;
        f2 t = c3 + c45, S5 = c12 + t, S6 = S5 + c0;
        f2 c01 = c0 + c1, c05 = c0 + c5, c15 = c1 + c5;
        o.n6[0] += S6;  o.n6[1] += S6;  o.n6[2] += c01; o.n6[3] += c45;
        o.n6[4] += S6;  o.n6[5] += S6;  o.n6[6] += c05;
        o.n5[0] += S5;  o.n5[1] += S5;  o.n5[2] += c12; o.n5[3] += c45;
        o.n5[4] += S5;  o.n5[5] += S5;  o.n5[6] += c15; o.n5[7] += S5;
    }
    // K3: all 8 masks = S33 - center - one distinct cell
    f2 S33 = (r2s + r3s) + r4s;
    f2 T = S33 - cen4;
    o.n3[0] = T - cen3; o.n3[1] = T - cen7; o.n3[2] = T - cen5; o.n3[3] = T - cen1;
    o.n3[4] = T - cen0; o.n3[5] = T - cen6; o.n3[6] = T - cen8; o.n3[7] = T - cen2;
    return o;
}

// class index per mask into per-class constants; counts {7,9,10,11,13,16}
__constant__ __device__ const int CI4[8] = {1, 1, 1, 1, 2, 2, 2, 2};
__constant__ __device__ const int CI5[8] = {3, 3, 3, 3, 4, 4, 4, 4};
__constant__ __device__ const int CI6[7] = {4, 4, 4, 4, 5, 5, 5};

template <bool PAIR>
__device__ __forceinline__ void ssum_from_nc2(const NC2& a, const f2* negA,
                                              const f2* s2m, f2& sD, f2& sC) {
    f2 sd = 0.0f, sc = 0.0f;
#pragma unroll
    for (int k = 0; k < 8; k++) {
        if constexpr (PAIR) pair_term2(a.n3[k], negA[0], s2m[0], sd, sc);
        else end_term2(a.n3[k], sd);
    }
#pragma unroll
    for (int k = 0; k < 8; k++) {
        if constexpr (PAIR) pair_term2(a.n4[k], negA[CI4[k]], s2m[CI4[k]], sd, sc);
        else end_term2(a.n4[k], sd);
    }
#pragma unroll
    for (int k = 0; k < 8; k++) {
        if constexpr (PAIR) pair_term2(a.n5[k], negA[CI5[k]], s2m[CI5[k]], sd, sc);
        else end_term2(a.n5[k], sd);
    }
#pragma unroll
    for (int k = 0; k < 7; k++) {
        if constexpr (PAIR) pair_term2(a.n6[k], negA[CI6[k]], s2m[CI6[k]], sd, sc);
        else end_term2(a.n6[k], sd);
    }
    sD = sd;
    sC = sc;
}

// ---------------- cross-conv 4px/thread helper -------------------------------
__device__ __forceinline__ void cross4(const float* __restrict__ xp, int idx,
                                       int y, int c, float4& ctr, float t[4]) {
    const float4* v = (const float4*)(xp + idx);
    ctr = v[0];
    float4 up = (y > 0) ? *(const float4*)(xp + idx - W)
                        : make_float4(0, 0, 0, 0);
    float4 dn = (y < H - 1) ? *(const float4*)(xp + idx + W)
                            : make_float4(0, 0, 0, 0);
    float lf = (c > 0) ? xp[idx - 1] : 0.0f;
    float rt = (c < W - 4) ? xp[idx + 4] : 0.0f;
    t[0] = (up.x + dn.x) + (lf + ctr.y);
    t[1] = (up.y + dn.y) + (ctr.x + ctr.z);
    t[2] = (up.z + dn.z) + (ctr.y + ctr.w);
    t[3] = (up.w + dn.w) + (ctr.z + rt);
}

// ---------------- erosion chain phases (fused cooperative kernel) ------------
__device__ __forceinline__ void cmax_phase(const float* __restrict__ xP,
                                           const float* __restrict__ xG,
                                           float4* __restrict__ partial) {
    float mtP = 0, mtG = 0, mrP = 0, mrG = 0;
    for (int T = blockIdx.x * 256 + threadIdx.x; T < NPIX / 4; T += NB1 * 256) {
        int idx = T * 4;
        int i = idx & (HW - 1);
        int y = i >> 9;
        int c = i & (W - 1);
        float4 ctr;
        float t[4];
        cross4(xP, idx, y, c, ctr, t);
        mtP = fmaxf(mtP, fmaxf(fmaxf(t[0], t[1]), fmaxf(t[2], t[3])));
        mrP = fmaxf(mrP, fmaxf(fmaxf(ctr.x, ctr.y), fmaxf(ctr.z, ctr.w)));
        cross4(xG, idx, y, c, ctr, t);
        mtG = fmaxf(mtG, fmaxf(fmaxf(t[0], t[1]), fmaxf(t[2], t[3])));
        mrG = fmaxf(mrG, fmaxf(fmaxf(ctr.x, ctr.y), fmaxf(ctr.z, ctr.w)));
    }
    mtP = wave_max(mtP); mtG = wave_max(mtG);
    mrP = wave_max(mrP); mrG = wave_max(mrG);
    __shared__ float red[4][4];
    int tid = threadIdx.x;
    __syncthreads();  // red[] reuse across phases
    if ((tid & 63) == 0) {
        int w = tid >> 6;
        red[w][0] = mtP; red[w][1] = mtG; red[w][2] = mrP; red[w][3] = mrG;
    }
    __syncthreads();
    if (tid == 0) {
        float4 r;
        r.x = fmaxf(fmaxf(red[0][0], red[1][0]), fmaxf(red[2][0], red[3][0]));
        r.y = fmaxf(fmaxf(red[0][1], red[1][1]), fmaxf(red[2][1], red[3][1]));
        r.z = fmaxf(fmaxf(red[0][2], red[1][2]), fmaxf(red[2][2], red[3][2]));
        r.w = fmaxf(fmaxf(red[0][3], red[1][3]), fmaxf(red[2][3], red[3][3]));
        partial[blockIdx.x] = r;
    }
}

__device__ __forceinline__ void erode_phase(
    const float* __restrict__ xP, const float* __restrict__ xG,
    const float4* __restrict__ PM,
    float* __restrict__ yP, float* __restrict__ yG,
    float* ymaxP, float* ymaxG, float* rmaxP, float* rmaxG) {
    // redundant per-block PM reduce (16KB, L2-resident)
    float a = 0, bm = 0, c4 = 0, d4 = 0;
    {
        int t = threadIdx.x;
#pragma unroll
        for (int k = 0; k < NB1 / 256; k++) {
            float4 p = PM[t + k * 256];
            a = fmaxf(a, p.x); bm = fmaxf(bm, p.y);
            c4 = fmaxf(c4, p.z); d4 = fmaxf(d4, p.w);
        }
        a = wave_max(a); bm = wave_max(bm); c4 = wave_max(c4); d4 = wave_max(d4);
        __shared__ float red[4][4];
        __syncthreads();  // red[] reuse across phases
        if ((t & 63) == 0) {
            int w = t >> 6;
            red[w][0] = a; red[w][1] = bm; red[w][2] = c4; red[w][3] = d4;
        }
        __syncthreads();
        a  = fmaxf(fmaxf(red[0][0], red[1][0]), fmaxf(red[2][0], red[3][0]));
        bm = fmaxf(fmaxf(red[0][1], red[1][1]), fmaxf(red[2][1], red[3][1]));
        c4 = fmaxf(fmaxf(red[0][2], red[1][2]), fmaxf(red[2][2], red[3][2]));
        d4 = fmaxf(fmaxf(red[0][3], red[1][3]), fmaxf(red[2][3], red[3][3]));
    }
    const float tP_max = a, tG_max = bm;
    const float invP = rcpf(tP_max + 1e-8f);
    const float invG = rcpf(tG_max + 1e-8f);

    for (int T = blockIdx.x * 256 + threadIdx.x; T < NPIX / 4; T += NB1 * 256) {
        int idx = T * 4;
        int i = idx & (HW - 1);
        int y = i >> 9;
        int c = i & (W - 1);
        float4 ctr;
        float t[4], o[4];
        cross4(xP, idx, y, c, ctr, t);
#pragma unroll
        for (int k = 0; k < 4; k++) o[k] = sig_er(t[k] * invP);
        *(float4*)(yP + idx) = make_float4(o[0], o[1], o[2], o[3]);
        cross4(xG, idx, y, c, ctr, t);
#pragma unroll
        for (int k = 0; k < 4; k++) o[k] = sig_er(t[k] * invG);
        *(float4*)(yG + idx) = make_float4(o[0], o[1], o[2], o[3]);
    }
    if (blockIdx.x == 0 && threadIdx.x == 0) {
        *ymaxP = sig_er(tP_max * invP);
        *ymaxG = sig_er(tG_max * invG);
        *rmaxP = c4;
        *rmaxG = d4;
    }
}

// Fused: cmax(pred,gt) -> erode -> cmax(P1,G1) -> erode -> consts.
// 1024 blocks x 256 thr = 4 blocks/CU co-resident. CST aliases PM (same
// address; PM dead after last erode, write is after the final grid.sync).
__global__ __launch_bounds__(256, 4) void erosion_chain_kernel(
    const float* __restrict__ pred, const float* __restrict__ gt,
    float* __restrict__ P1, float* __restrict__ G1,
    float* __restrict__ P2, float* __restrict__ G2,
    float4* PM, float* S) {
    cg::grid_group grid = cg::this_grid();
    cmax_phase(pred, gt, PM);
    grid.sync();
    erode_phase(pred, gt, PM, P1, G1, S + 1, S + 4, S + 0, S + 3);
    grid.sync();
    cmax_phase(P1, G1, PM);
    grid.sync();
    erode_phase(P1, G1, PM, P2, G2, S + 2, S + 5, S + 12, S + 13);
    grid.sync();
    // consts: CST layout lvl*24 + cls*2 + img -> negA; +12 -> s2m
    if (blockIdx.x == 0 && threadIdx.x < 36) {
        float* CST = (float*)PM;
        int t = threadIdx.x;
        int lvl = t / 12, rem = t % 12, cls = rem >> 1, img = rem & 1;
        const float cntf[6] = {7.0f, 9.0f, 10.0f, 11.0f, 13.0f, 16.0f};
        float M = S[lvl + 3 * img];
        float cm = fmaf(cntf[cls] * M, CC, -CC);
        float m = 0.5f * (cm - CC);
        CST[lvl * 24 + cls * 2 + img] = -(CC + m);
        CST[lvl * 24 + 12 + cls * 2 + img] = exp2f_n(m);
    }
}

// ---------------- cp_main: interior 2px/thread + edge ring -------------------
__global__ __launch_bounds__(256, 4) void cp_main_kernel(
    const float* __restrict__ x0P, const float* __restrict__ x0G,
    const float* __restrict__ x1P, const float* __restrict__ x1G,
    const float* __restrict__ x2P, const float* __restrict__ x2G,
    const float* __restrict__ S, const float* __restrict__ CST,
    int lvl_base, int plane_lvl0, __half* __restrict__ cp) {
    __shared__ f2 win[37][23];
    const int lvl = lvl_base + (blockIdx.z >> 3);
    const int b = blockIdx.z & 7;
    const float* xP = (lvl == 0) ? x0P : (lvl == 1) ? x1P : x2P;
    const float* xG = (lvl == 0) ? x0G : (lvl == 1) ? x1G : x2G;
    const float MP = S[lvl], MG = S[3 + lvl];
    __half* cpb = cp + (size_t)(4 * (lvl - plane_lvl0)) * NPIX;
    const int tid = threadIdx.y * 16 + threadIdx.x;
    const int ty = threadIdx.y, tx = threadIdx.x;
    const f2* cbase = (const f2*)(CST + lvl * 24);

    if (blockIdx.x < N_INT) {
        const int txB = 1 + (int)blockIdx.x % 30;
        const int tyB = 1 + (int)blockIdx.x / 30;
        const int ox0 = txB * 16, oy0 = tyB * 32;
        const float* pb = xP + b * HW + (oy0 - 3) * W + (ox0 - 3);
        const float* gb = xG + b * HW + (oy0 - 3) * W + (ox0 - 3);
        {   // 37x21 fill, strength-reduced indexing (256 = 12*21+4)
            int i = tid, r = tid / 21, c = tid - (tid / 21) * 21;
            while (i < 37 * 21) {
                win[r][c] = mk2(pb[r * W + c], gb[r * W + c]);
                i += 256; c += 4; r += 12;
                if (c >= 21) { c -= 21; r += 1; }
            }
        }
        __syncthreads();
        f2 negA[6], s2m[6];
#pragma unroll
        for (int c = 0; c < 6; c++) { negA[c] = cbase[c]; s2m[c] = cbase[6 + c]; }
        int o = b * HW + (oy0 + ty) * W + (ox0 + tx);
        {
            f2 sd, sc;
            NC2 a = sweep2<23>(&win[ty][tx]);
            ssum_from_nc2<true>(a, negA, s2m, sd, sc);
            H4 v;
            v.h[0] = __float2half(sig_cp(a.v.x * sd.x));
            v.h[1] = __float2half(sig_cp(a.v.y * sd.y));
            v.h[2] = __float2half(sig_cp((MP - a.v.x) * sc.x));
            v.h[3] = __float2half(sig_cp((MG - a.v.y) * sc.y));
            *(uint64_t*)(cpb + (size_t)o * 4) = v.u;
        }
        o += 16 * W;
        {
            f2 sd, sc;
            NC2 a = sweep2<23>(&win[ty + 16][tx]);
            ssum_from_nc2<true>(a, negA, s2m, sd, sc);
            H4 v;
            v.h[0] = __float2half(sig_cp(a.v.x * sd.x));
            v.h[1] = __float2half(sig_cp(a.v.y * sd.y));
            v.h[2] = __float2half(sig_cp((MP - a.v.x) * sc.x));
            v.h[3] = __float2half(sig_cp((MG - a.v.y) * sc.y));
            *(uint64_t*)(cpb + (size_t)o * 4) = v.u;
        }
    } else {
        const int e = (int)blockIdx.x - N_INT;
        int tx16, ty16;
        if (e < 64) {
            ty16 = e >> 1;
            tx16 = (e & 1) ? 31 : 0;
        } else {
            int e2 = e - 64;
            int r = e2 / 30;
            ty16 = (r == 0) ? 0 : (r == 1) ? 1 : (r == 2) ? 30 : 31;
            tx16 = 1 + e2 % 30;
        }
        const int ox0 = tx16 * 16, oy0 = ty16 * 16;
        const int o = b * HW + (oy0 + ty) * W + (ox0 + tx);
        const bool fastw = (tx16 >= 1) & (tx16 <= 30) & (ty16 >= 1) & (ty16 <= 30);
        if (fastw) {
            const float* pb = xP + b * HW + (oy0 - 3) * W + (ox0 - 3);
            const float* gb = xG + b * HW + (oy0 - 3) * W + (ox0 - 3);
            {
                int i = tid, r = tid / 21, c = tid - (tid / 21) * 21;
                while (i < 21 * 21) {
                    win[r][c] = mk2(pb[r * W + c], gb[r * W + c]);
                    i += 256; c += 4; r += 12;
                    if (c >= 21) { c -= 21; r += 1; }
                }
            }
            __syncthreads();
            f2 negA[6], s2m[6], sd, sc;
#pragma unroll
            for (int c = 0; c < 6; c++) { negA[c] = cbase[c]; s2m[c] = cbase[6 + c]; }
            NC2 a = sweep2<23>(&win[ty][tx]);
            ssum_from_nc2<true>(a, negA, s2m, sd, sc);
            H4 v;
            v.h[0] = __float2half(sig_cp(a.v.x * sd.x));
            v.h[1] = __float2half(sig_cp(a.v.y * sd.y));
            v.h[2] = __float2half(sig_cp((MP - a.v.x) * sc.x));
            v.h[3] = __float2half(sig_cp((MG - a.v.y) * sc.y));
            *(uint64_t*)(cpb + (size_t)o * 4) = v.u;
        } else {
            const float* pb = xP + b * HW;
            const float* gb = xG + b * HW;
            // phase A: direct planes
            {
                int i = tid, r = tid / 21, c = tid - (tid / 21) * 21;
                while (i < 21 * 21) {
                    int pr = oy0 - 2 + r;  // padded coords (0..513 valid)
                    int pc = ox0 - 2 + c;
                    f2 v;
                    if (pr < 0 || pr > H + 1 || pc < 0 || pc > W + 1) {
                        v = 0.0f;  // conv zero-pad
                    } else if (pr == 0 || pr == H + 1 || pc == 0 || pc == W + 1) {
                        v = 1.0f;  // image 1-pad
                    } else {
                        v = mk2(pb[(pr - 1) * W + (pc - 1)], gb[(pr - 1) * W + (pc - 1)]);
                    }
                    win[r][c] = v;
                    i += 256; c += 4; r += 12;
                    if (c >= 21) { c -= 21; r += 1; }
                }
            }
            __syncthreads();
            f2 sd, sc, junk;
            NC2 a = sweep2<23>(&win[ty][tx]);
            ssum_from_nc2<false>(a, nullptr, nullptr, sd, junk);
            f2 vD = a.v;
            __half2* po = (__half2*)(cpb + (size_t)o * 4);
            po[0] = __halves2half2(__float2half(sig_cp(vD.x * sd.x)),
                                   __float2half(sig_cp(vD.y * sd.y)));
            __syncthreads();  // all reads of direct planes done
            // phase B: complement planes
            {
                int i = tid, r = tid / 21, c = tid - (tid / 21) * 21;
                while (i < 21 * 21) {
                    int pr = oy0 - 2 + r;
                    int pc = ox0 - 2 + c;
                    f2 v;
                    if (pr < 0 || pr > H + 1 || pc < 0 || pc > W + 1) {
                        v = 0.0f;
                    } else if (pr == 0 || pr == H + 1 || pc == 0 || pc == W + 1) {
                        v = 1.0f;
                    } else {
                        v = mk2(MP - pb[(pr - 1) * W + (pc - 1)],
                                MG - gb[(pr - 1) * W + (pc - 1)]);
                    }
                    win[r][c] = v;
                    i += 256; c += 4; r += 12;
                    if (c >= 21) { c -= 21; r += 1; }
                }
            }
            __syncthreads();
            NC2 ac = sweep2<23>(&win[ty][tx]);
            ssum_from_nc2<false>(ac, nullptr, nullptr, sc, junk);
            po[1] = __halves2half2(__float2half(sig_cp(ac.v.x * sc.x)),
                                   __float2half(sig_cp(ac.v.y * sc.y)));
        }
    }
}

// ---------------- dil_diff: 2 cols/thread, 3-row ring, interleaved f16 -------
// 512 blocks per level: block r -> (b = r>>6, rowgroup = r&63); tid -> column
// pair x0 = 2*tid. 4 record loads per row cover 2 output columns.
__global__ __launch_bounds__(256, 4) void dil_diff2_kernel(
    const __half* __restrict__ cp, float* __restrict__ partial) {
    const int plane_grp = blockIdx.x >> 9;  // 512 blocks per level
    const int r = blockIdx.x & 511;
    const __half* cpb = cp + (size_t)(4 * plane_grp) * NPIX;
    const int x0 = threadIdx.x << 1;
    const int y0 = (r & 63) << 3;
    const int b = r >> 6;
    const __half* pb = cpb + (size_t)b * HW * 4;

    float4 ring0[3], ring1[3];
    float s = 0.0f;
#pragma unroll
    for (int j = 0; j < 10; j++) {
        int yy = y0 - 1 + j;
        float4 a0 = make_float4(0.f, 0.f, 0.f, 0.f);
        float4 a1 = a0;
        if (yy >= 0 && yy < H) {  // wave-uniform
            const __half* row = pb + (size_t)yy * (W * 4);
            float4 f0 = h4_to_f4(*(const uint64_t*)(row + (size_t)x0 * 4));
            float4 f1 = h4_to_f4(*(const uint64_t*)(row + (size_t)(x0 + 1) * 4));
            float4 lf = make_float4(0.f, 0.f, 0.f, 0.f), rt = lf;
            if (x0 > 0)
                lf = h4_to_f4(*(const uint64_t*)(row + (size_t)(x0 - 1) * 4));
            if (x0 + 2 < W)
                rt = h4_to_f4(*(const uint64_t*)(row + (size_t)(x0 + 2) * 4));
            a0 = f4_add(f4_add(lf, f0), f1);   // (l + m) + r, bit-exact
            a1 = f4_add(f4_add(f0, f1), rt);
        }
        ring0[j % 3] = a0; ring1[j % 3] = a1;
        if (j >= 2) {
            float4 v0 = f4_add(f4_add(ring0[(j - 2) % 3], ring0[(j - 1) % 3]),
                               ring0[j % 3]);
            float4 v1 = f4_add(f4_add(ring1[(j - 2) % 3], ring1[(j - 1) % 3]),
                               ring1[j % 3]);
            float d1 = fminf(v0.x, 1.0f) - fminf(v0.y, 1.0f);
            float d2 = fminf(v0.z, 1.0f) - fminf(v0.w, 1.0f);
            s += fmaf(d1, d1, d2 * d2);
            d1 = fminf(v1.x, 1.0f) - fminf(v1.y, 1.0f);
            d2 = fminf(v1.z, 1.0f) - fminf(v1.w, 1.0f);
            s += fmaf(d1, d1, d2 * d2);
        }
    }
    s = wave_sum(s);
    __shared__ float red[4];
    int tid = threadIdx.x;
    if ((tid & 63) == 0) red[tid >> 6] = s;
    __syncthreads();
    if (tid == 0) partial[blockIdx.x] = (red[0] + red[1]) + (red[2] + red[3]);
}

// ---------------- final: sum 1536 partials, /B -------------------------------
__global__ __launch_bounds__(1024) void finalize_kernel(
    const float* __restrict__ PS, float* out) {
    int t = threadIdx.x;
    float s = PS[t] + ((t < 512) ? PS[t + 1024] : 0.0f);
    s = wave_sum(s);
    __shared__ float red[16];
    if ((t & 63) == 0) red[t >> 6] = s;
    __syncthreads();
    if (t == 0) {
        float tot = 0.0f;
#pragma unroll
        for (int i = 0; i < 16; i++) tot += red[i];
        out[0] = tot * (1.0f / (float)B);
    }
}

// ---------------- launch -----------------------------------------------------
extern "C" void kernel_launch(void* const* d_in, const int* in_sizes, int n_in,
                              void* d_out, int out_size, void* d_ws, size_t ws_size,
                              hipStream_t stream) {
    (void)in_sizes; (void)n_in; (void)out_size;
    const float* pred = (const float*)d_in[0];
    const float* gt   = (const float*)d_in[1];
    float* out = (float*)d_out;

    // ws (floats): S[64] | PM[4*NB1] | PS[3*NBD] | P1,G1,P2,G2 | CP (f16)
    // CST (72 floats) aliases the PM region (dead after last erode phase).
    float* S  = (float*)d_ws;
    float4* PM = (float4*)(S + 64);
    float* CST = S + 64;
    float* PS = S + 64 + 4 * NB1;
    float* P1 = PS + 3 * NBD;
    float* G1 = P1 + NPIX;
    float* P2 = G1 + NPIX;
    float* G2 = P2 + NPIX;
    __half* CP = (__half*)(G2 + NPIX);

    // merged path needs 12 f16 CP planes (48MB); fallback needs 4
    const size_t base_b = (size_t)(64 + 4 * NB1 + 3 * NBD) * 4 +
                          (size_t)4 * NPIX * 4;
    const bool merged = ws_size >= base_b + (size_t)12 * NPIX * 2;

    const dim3 b1(256);
    const dim3 b2(16, 16, 1);

    // fused erosion chain (cooperative): cmax -> erode -> cmax -> erode -> consts
    {
        void* kargs[] = {(void*)&pred, (void*)&gt, (void*)&P1, (void*)&G1,
                         (void*)&P2, (void*)&G2, (void*)&PM, (void*)&S};
        hipLaunchCooperativeKernel((const void*)erosion_chain_kernel,
                                   dim3(NB1), b1, kargs, 0, stream);
    }

    if (merged) {
        cp_main_kernel<<<dim3(GRID_X, 1, 3 * B), b2, 0, stream>>>(
            pred, gt, P1, G1, P2, G2, S, CST, 0, 0, CP);
        dil_diff2_kernel<<<dim3(3 * 512), b1, 0, stream>>>(CP, PS);
    } else {
        for (int lvl = 0; lvl < 3; lvl++) {
            cp_main_kernel<<<dim3(GRID_X, 1, B), b2, 0, stream>>>(
                pred, gt, P1, G1, P2, G2, S, CST, lvl, lvl, CP);
            dil_diff2_kernel<<<dim3(512), b1, 0, stream>>>(CP, PS + lvl * 512);
        }
    }

    finalize_kernel<<<1, 1024, 0, stream>>>(PS, out);
}

// Round 5
// 256.202 us; speedup vs baseline: 2.7551x; 2.7551x over previous
//
#include <hip/hip_runtime.h>
#include <hip/hip_fp16.h>
#include <cstdint>

// Problem constants (setup_inputs: B=8, H=W=512, num_erosions=2)
static constexpr int B = 8;
static constexpr int H = 512;
static constexpr int W = 512;
static constexpr int HW = H * W;
static constexpr int NPIX = B * HW;
static constexpr int NB1 = 1024;  // blocks for cross_max partials
static constexpr int NBD = 1024;  // legacy partial stride (finalize layout)

// cp_main tiling: interior = 16x32 tiles (2 px/thread), edge ring = 16x16
static constexpr int N_INT = 30 * 14;   // txB in [1,30], tyB in [1,14]
static constexpr int N_EDGE = 64 + 120; // 2 cols x 32 + 4 rows x 30
static constexpr int GRID_X = N_INT + N_EDGE;  // 604

// 10*log2(e): sigmoid(10*z) = 1/(1+2^(-CC*z))
static constexpr float CC = 14.4269504088896f;

// ---------------- helpers ----------------------------------------------------
// R14: interleaved CP records (WRITE 419->49MB). R15: f2 (P,G) VOP3P packing.
// R16: 2px/thread interior + hoisted consts -> 164us, VALUBusy 82% (issue
//   envelope; trans 62exp+124rcp/output irreducible — product-rcp trick
//   rejected: w*s=2^(CC(nc-1)) overflows f32, fused form NaNs where the
//   separate rcp(inf)=0 is benign).
// R17 FAILED: cooperative grid.sync costs ~100us+ each on this runtime
//   (erosion chain 477us @ 1.6% VALUBusy) — separate dispatches ARE the
//   cheap barrier here. R18 reverts to 5-dispatch erosion chain; keeps
//   R17's dil_diff (2 cols/thread ring) + strength-reduced fills.
__device__ __forceinline__ float rcpf(float x) { return __builtin_amdgcn_rcpf(x); }
__device__ __forceinline__ float exp2f_n(float x) { return __builtin_amdgcn_exp2f(x); }

typedef __attribute__((ext_vector_type(2))) float f2;

__device__ __forceinline__ f2 mk2(float a, float b) { f2 r; r.x = a; r.y = b; return r; }
__device__ __forceinline__ f2 exp2_2(f2 v) {
    f2 r; r.x = exp2f_n(v.x); r.y = exp2f_n(v.y); return r;
}
__device__ __forceinline__ f2 rcp_2(f2 v) {
    f2 r; r.x = rcpf(v.x); r.y = rcpf(v.y); return r;
}
#if defined(__has_builtin)
#if __has_builtin(__builtin_elementwise_fma)
#define FMA2(a, b, c) __builtin_elementwise_fma((a), (b), (c))
#endif
#endif
#ifndef FMA2
__device__ __forceinline__ f2 fma2_(f2 a, f2 b, f2 c) {
    f2 r; r.x = fmaf(a.x, b.x, c.x); r.y = fmaf(a.y, b.y, c.y); return r;
}
#define FMA2(a, b, c) fma2_((a), (b), (c))
#endif

__device__ __forceinline__ float sig_cp(float x) {  // sigmoid(10(x-0.5))
    return rcpf(1.0f + exp2f_n(fmaf(x, -CC, 0.5f * CC)));
}
__device__ __forceinline__ float sig_er(float r) {  // sigmoid(10(r-0.7))
    return rcpf(1.0f + exp2f_n(fmaf(r, -CC, 0.7f * CC)));
}
// Shared-exp complement pair (R12): one exp per (direct, complement) pair.
__device__ __forceinline__ void pair_term2(f2 nc, f2 negA, f2 s2m,
                                           f2& sd, f2& sc) {
    const f2 CC2 = CC;
    const f2 one2 = 1.0f;
    f2 w = exp2_2(FMA2(nc, CC2, negA));
    sd += rcp_2(FMA2(w, s2m, one2));
    sc += w * rcp_2(w + s2m);
}
// plain direct-only sigmoid (padded edge phases), f2 lanes (P, G)
__device__ __forceinline__ void end_term2(f2 nc, f2& sd) {
    const f2 CC2 = CC;
    const f2 nCC2 = -CC;
    const f2 one2 = 1.0f;
    sd += rcp_2(one2 + exp2_2(FMA2(nc, CC2, nCC2)));
}
__device__ __forceinline__ float wave_max(float m) {
#pragma unroll
    for (int o = 32; o > 0; o >>= 1) m = fmaxf(m, __shfl_down(m, o, 64));
    return m;
}
__device__ __forceinline__ float wave_sum(float s) {
#pragma unroll
    for (int o = 32; o > 0; o >>= 1) s += __shfl_down(s, o, 64);
    return s;
}

// packed 4x f16 pixel record (planes interleaved)
union H4 {
    uint64_t u;
    __half2 h2[2];
    __half h[4];
};

__device__ __forceinline__ float4 h4_to_f4(uint64_t u) {
    H4 v; v.u = u;
    float2 p0 = __half22float2(v.h2[0]);
    float2 p1 = __half22float2(v.h2[1]);
    return make_float4(p0.x, p0.y, p1.x, p1.y);
}
__device__ __forceinline__ float4 f4_add(float4 a, float4 b) {
    return make_float4(a.x + b.x, a.y + b.y, a.z + b.z, a.w + b.w);
}

// ---------------- row-sweep mask conv sums (f2: lanes = P,G) -----------------
struct NC2 {
    f2 n3[8], n4[8], n5[8], n6[7];
    f2 v;  // center value w[3][3]
};

template <int STRIDE>
__device__ __forceinline__ NC2 sweep2(const f2* rp) {
    NC2 o;
    f2 r2s, r3s, r4s;
    f2 cen0, cen1, cen2, cen3, cen4, cen5, cen6, cen7, cen8;
    {   // win row 0 = K6 row 0
        f2 c0 = rp[0], c1 = rp[1], c2 = rp[2], c3 = rp[3], c4 = rp[4], c5 = rp[5];
        f2 c45 = c4 + c5, c01 = c0 + c1;
        f2 S6 = (c01 + (c2 + c3)) + c45;
        o.n6[0] = c45; o.n6[1] = c01; o.n6[2] = S6; o.n6[3] = S6;
        o.n6[4] = S6;  o.n6[5] = S6;  o.n6[6] = S6;
    }
    rp += STRIDE;
    {   // win row 1 = K6 r1, K5 r0, K4 r0
        f2 c0 = rp[0], c1 = rp[1], c2 = rp[2], c3 = rp[3], c4 = rp[4], c5 = rp[5];
        f2 c45 = c4 + c5, c12 = c1 + c2, c34 = c3 + c4;
        f2 S4 = c12 + c34, S5 = S4 + c5;
        f2 c15 = c1 + c5, c05 = c0 + c5, c14 = c1 + c4;
        o.n6[0] += c5;  o.n6[1] += c0;  o.n6[2] += c05; o.n6[3] += c05;
        o.n6[4] += c0;  o.n6[5] += c5;  o.n6[6] += c05;
        o.n5[0] = c45; o.n5[1] = c12; o.n5[2] = S5; o.n5[3] = S5;
        o.n5[4] = S5;  o.n5[5] = S5;  o.n5[6] = S5; o.n5[7] = c15;
        o.n4[0] = c34; o.n4[1] = c12; o.n4[2] = S4; o.n4[3] = S4;
        o.n4[4] = c14; o.n4[5] = S4;  o.n4[6] = S4; o.n4[7] = S4;
    }
    rp += STRIDE;
    {   // win row 2 = K6 r2, K5 r1, K4 r1, K3 r0
        f2 c0 = rp[0], c1 = rp[1], c2 = rp[2], c3 = rp[3], c4 = rp[4], c5 = rp[5];
        f2 c05 = c0 + c5, c15 = c1 + c5, c14 = c1 + c4;
        r2s = (c2 + c3) + c4;
        cen0 = c2; cen1 = c3; cen2 = c4;
        o.n6[0] += c5;  o.n6[1] += c0;  o.n6[2] += c0;  o.n6[3] += c5;
        o.n6[4] += c0;  o.n6[5] += c5;  o.n6[6] += c05;
        o.n5[0] += c5;  o.n5[1] += c1;  o.n5[2] += c15; o.n5[3] += c15;
        o.n5[4] += c1;  o.n5[5] += c5;  o.n5[6] += c15; o.n5[7] += c15;
        o.n4[0] += c4;  o.n4[1] += c1;  o.n4[2] += c14; o.n4[3] += c14;
        o.n4[4] += c14; o.n4[5] += c4;  o.n4[6] += c14; o.n4[7] += c1;
    }
    rp += STRIDE;
    {   // win row 3 = K6 r3, K5 r2, K4 r2, K3 r1 (center row)
        f2 c0 = rp[0], c1 = rp[1], c2 = rp[2], c3 = rp[3], c4 = rp[4], c5 = rp[5];
        f2 c05 = c0 + c5, c15 = c1 + c5, c14 = c1 + c4;
        r3s = (c2 + c3) + c4;
        cen3 = c2; cen4 = c3; cen5 = c4;
        o.v = c3;
        o.n6[0] += c5;  o.n6[1] += c0;  o.n6[2] += c0;  o.n6[3] += c5;
        o.n6[4] += c0;  o.n6[5] += c5;  o.n6[6] += c05;
        o.n5[0] += c5;  o.n5[1] += c1;  o.n5[2] += c1;  o.n5[3] += c5;
        o.n5[4] += c1;  o.n5[5] += c5;  o.n5[6] += c15; o.n5[7] += c15;
        o.n4[0] += c14; o.n4[1] += c14; o.n4[2] += c4;  o.n4[3] += c1;
        o.n4[4] += c14; o.n4[5] += c4;  o.n4[6] += c14; o.n4[7] += c1;
    }
    rp += STRIDE;
    {   // win row 4 = K6 r4, K5 r3, K4 r3, K3 r2
        f2 c0 = rp[0], c1 = rp[1], c2 = rp[2], c3 = rp[3], c4 = rp[4], c5 = rp[5];
        f2 c05 = c0 + c5, c15 = c1 + c5, c12 = c1 + c2, c34 = c3 + c4;
        f2 S4 = c12 + c34, c14 = c1 + c4;
        r4s = (c2 + c3) + c4;
        cen6 = c2; cen7 = c3; cen8 = c4;
        o.n6[0] += c05; o.n6[1] += c05; o.n6[2] += c0;  o.n6[3] += c5;
        o.n6[4] += c0;  o.n6[5] += c5;  o.n6[6] += c05;
        o.n5[0] += c15; o.n5[1] += c15; o.n5[2] += c1;  o.n5[3] += c5;
        o.n5[4] += c1;  o.n5[5] += c5;  o.n5[6] += c15; o.n5[7] += c15;
        o.n4[0] += S4;  o.n4[1] += S4;  o.n4[2] += c34; o.n4[3] += c12;
        o.n4[4] += S4;  o.n4[5] += S4;  o.n4[6] += c14; o.n4[7] += S4;
    }
    rp += STRIDE;
    {   // win row 5 = K6 r5, K5 r4
        f2 c0 = rp[0], c1 = rp[1], c2 = rp[2], c3 = rp[3], c4 = rp[4], c5 = rp[5];
        f2 c45 = c4 + c5, c12 = c1 + c2;
        f2 t = c3 + c45, S5 = c12 + t, S6 = S5 + c0;
        f2 c01 = c0 + c1, c05 = c0 + c5, c15 = c1 + c5;
        o.n6[0] += S6;  o.n6[1] += S6;  o.n6[2] += c01; o.n6[3] += c45;
        o.n6[4] += S6;  o.n6[5] += S6;  o.n6[6] += c05;
        o.n5[0] += S5;  o.n5[1] += S5;  o.n5[2] += c12; o.n5[3] += c45;
        o.n5[4] += S5;  o.n5[5] += S5;  o.n5[6] += c15; o.n5[7] += S5;
    }
    // K3: all 8 masks = S33 - center - one distinct cell
    f2 S33 = (r2s + r3s) + r4s;
    f2 T = S33 - cen4;
    o.n3[0] = T - cen3; o.n3[1] = T - cen7; o.n3[2] = T - cen5; o.n3[3] = T - cen1;
    o.n3[4] = T - cen0; o.n3[5] = T - cen6; o.n3[6] = T - cen8; o.n3[7] = T - cen2;
    return o;
}

// class index per mask into per-class constants; counts {7,9,10,11,13,16}
__constant__ __device__ const int CI4[8] = {1, 1, 1, 1, 2, 2, 2, 2};
__constant__ __device__ const int CI5[8] = {3, 3, 3, 3, 4, 4, 4, 4};
__constant__ __device__ const int CI6[7] = {4, 4, 4, 4, 5, 5, 5};

template <bool PAIR>
__device__ __forceinline__ void ssum_from_nc2(const NC2& a, const f2* negA,
                                              const f2* s2m, f2& sD, f2& sC) {
    f2 sd = 0.0f, sc = 0.0f;
#pragma unroll
    for (int k = 0; k < 8; k++) {
        if constexpr (PAIR) pair_term2(a.n3[k], negA[0], s2m[0], sd, sc);
        else end_term2(a.n3[k], sd);
    }
#pragma unroll
    for (int k = 0; k < 8; k++) {
        if constexpr (PAIR) pair_term2(a.n4[k], negA[CI4[k]], s2m[CI4[k]], sd, sc);
        else end_term2(a.n4[k], sd);
    }
#pragma unroll
    for (int k = 0; k < 8; k++) {
        if constexpr (PAIR) pair_term2(a.n5[k], negA[CI5[k]], s2m[CI5[k]], sd, sc);
        else end_term2(a.n5[k], sd);
    }
#pragma unroll
    for (int k = 0; k < 7; k++) {
        if constexpr (PAIR) pair_term2(a.n6[k], negA[CI6[k]], s2m[CI6[k]], sd, sc);
        else end_term2(a.n6[k], sd);
    }
    sD = sd;
    sC = sc;
}

// ---------------- setup: per-(lvl,class,img) pair constants ------------------
// CST layout (floats): lvl*24 + cls*2 + img -> negA; +12 -> s2m.
__global__ void setup_consts_kernel(const float* __restrict__ S,
                                    float* __restrict__ CST) {
    int t = threadIdx.x;
    if (t < 36) {
        int lvl = t / 12, rem = t % 12, cls = rem >> 1, img = rem & 1;
        const float cntf[6] = {7.0f, 9.0f, 10.0f, 11.0f, 13.0f, 16.0f};
        float M = S[lvl + 3 * img];
        float cm = fmaf(cntf[cls] * M, CC, -CC);
        float m = 0.5f * (cm - CC);
        CST[lvl * 24 + cls * 2 + img] = -(CC + m);
        CST[lvl * 24 + 12 + cls * 2 + img] = exp2f_n(m);
    }
}

// ---------------- cp_main: interior 2px/thread + edge ring -------------------
__global__ __launch_bounds__(256, 4) void cp_main_kernel(
    const float* __restrict__ x0P, const float* __restrict__ x0G,
    const float* __restrict__ x1P, const float* __restrict__ x1G,
    const float* __restrict__ x2P, const float* __restrict__ x2G,
    const float* __restrict__ S, const float* __restrict__ CST,
    int lvl_base, int plane_lvl0, __half* __restrict__ cp) {
    __shared__ f2 win[37][23];
    const int lvl = lvl_base + (blockIdx.z >> 3);
    const int b = blockIdx.z & 7;
    const float* xP = (lvl == 0) ? x0P : (lvl == 1) ? x1P : x2P;
    const float* xG = (lvl == 0) ? x0G : (lvl == 1) ? x1G : x2G;
    const float MP = S[lvl], MG = S[3 + lvl];
    __half* cpb = cp + (size_t)(4 * (lvl - plane_lvl0)) * NPIX;
    const int tid = threadIdx.y * 16 + threadIdx.x;
    const int ty = threadIdx.y, tx = threadIdx.x;
    const f2* cbase = (const f2*)(CST + lvl * 24);

    if (blockIdx.x < N_INT) {
        const int txB = 1 + (int)blockIdx.x % 30;
        const int tyB = 1 + (int)blockIdx.x / 30;
        const int ox0 = txB * 16, oy0 = tyB * 32;
        const float* pb = xP + b * HW + (oy0 - 3) * W + (ox0 - 3);
        const float* gb = xG + b * HW + (oy0 - 3) * W + (ox0 - 3);
        {   // 37x21 fill, strength-reduced indexing (256 = 12*21+4)
            int i = tid, r = tid / 21, c = tid - (tid / 21) * 21;
            while (i < 37 * 21) {
                win[r][c] = mk2(pb[r * W + c], gb[r * W + c]);
                i += 256; c += 4; r += 12;
                if (c >= 21) { c -= 21; r += 1; }
            }
        }
        __syncthreads();
        f2 negA[6], s2m[6];
#pragma unroll
        for (int c = 0; c < 6; c++) { negA[c] = cbase[c]; s2m[c] = cbase[6 + c]; }
        int o = b * HW + (oy0 + ty) * W + (ox0 + tx);
        {
            f2 sd, sc;
            NC2 a = sweep2<23>(&win[ty][tx]);
            ssum_from_nc2<true>(a, negA, s2m, sd, sc);
            H4 v;
            v.h[0] = __float2half(sig_cp(a.v.x * sd.x));
            v.h[1] = __float2half(sig_cp(a.v.y * sd.y));
            v.h[2] = __float2half(sig_cp((MP - a.v.x) * sc.x));
            v.h[3] = __float2half(sig_cp((MG - a.v.y) * sc.y));
            *(uint64_t*)(cpb + (size_t)o * 4) = v.u;
        }
        o += 16 * W;
        {
            f2 sd, sc;
            NC2 a = sweep2<23>(&win[ty + 16][tx]);
            ssum_from_nc2<true>(a, negA, s2m, sd, sc);
            H4 v;
            v.h[0] = __float2half(sig_cp(a.v.x * sd.x));
            v.h[1] = __float2half(sig_cp(a.v.y * sd.y));
            v.h[2] = __float2half(sig_cp((MP - a.v.x) * sc.x));
            v.h[3] = __float2half(sig_cp((MG - a.v.y) * sc.y));
            *(uint64_t*)(cpb + (size_t)o * 4) = v.u;
        }
    } else {
        const int e = (int)blockIdx.x - N_INT;
        int tx16, ty16;
        if (e < 64) {
            ty16 = e >> 1;
            tx16 = (e & 1) ? 31 : 0;
        } else {
            int e2 = e - 64;
            int r = e2 / 30;
            ty16 = (r == 0) ? 0 : (r == 1) ? 1 : (r == 2) ? 30 : 31;
            tx16 = 1 + e2 % 30;
        }
        const int ox0 = tx16 * 16, oy0 = ty16 * 16;
        const int o = b * HW + (oy0 + ty) * W + (ox0 + tx);
        const bool fastw = (tx16 >= 1) & (tx16 <= 30) & (ty16 >= 1) & (ty16 <= 30);
        if (fastw) {
            const float* pb = xP + b * HW + (oy0 - 3) * W + (ox0 - 3);
            const float* gb = xG + b * HW + (oy0 - 3) * W + (ox0 - 3);
            {
                int i = tid, r = tid / 21, c = tid - (tid / 21) * 21;
                while (i < 21 * 21) {
                    win[r][c] = mk2(pb[r * W + c], gb[r * W + c]);
                    i += 256; c += 4; r += 12;
                    if (c >= 21) { c -= 21; r += 1; }
                }
            }
            __syncthreads();
            f2 negA[6], s2m[6], sd, sc;
#pragma unroll
            for (int c = 0; c < 6; c++) { negA[c] = cbase[c]; s2m[c] = cbase[6 + c]; }
            NC2 a = sweep2<23>(&win[ty][tx]);
            ssum_from_nc2<true>(a, negA, s2m, sd, sc);
            H4 v;
            v.h[0] = __float2half(sig_cp(a.v.x * sd.x));
            v.h[1] = __float2half(sig_cp(a.v.y * sd.y));
            v.h[2] = __float2half(sig_cp((MP - a.v.x) * sc.x));
            v.h[3] = __float2half(sig_cp((MG - a.v.y) * sc.y));
            *(uint64_t*)(cpb + (size_t)o * 4) = v.u;
        } else {
            const float* pb = xP + b * HW;
            const float* gb = xG + b * HW;
            // phase A: direct planes
            {
                int i = tid, r = tid / 21, c = tid - (tid / 21) * 21;
                while (i < 21 * 21) {
                    int pr = oy0 - 2 + r;  // padded coords (0..513 valid)
                    int pc = ox0 - 2 + c;
                    f2 v;
                    if (pr < 0 || pr > H + 1 || pc < 0 || pc > W + 1) {
                        v = 0.0f;  // conv zero-pad
                    } else if (pr == 0 || pr == H + 1 || pc == 0 || pc == W + 1) {
                        v = 1.0f;  // image 1-pad
                    } else {
                        v = mk2(pb[(pr - 1) * W + (pc - 1)], gb[(pr - 1) * W + (pc - 1)]);
                    }
                    win[r][c] = v;
                    i += 256; c += 4; r += 12;
                    if (c >= 21) { c -= 21; r += 1; }
                }
            }
            __syncthreads();
            f2 sd, sc, junk;
            NC2 a = sweep2<23>(&win[ty][tx]);
            ssum_from_nc2<false>(a, nullptr, nullptr, sd, junk);
            f2 vD = a.v;
            __half2* po = (__half2*)(cpb + (size_t)o * 4);
            po[0] = __halves2half2(__float2half(sig_cp(vD.x * sd.x)),
                                   __float2half(sig_cp(vD.y * sd.y)));
            __syncthreads();  // all reads of direct planes done
            // phase B: complement planes
            {
                int i = tid, r = tid / 21, c = tid - (tid / 21) * 21;
                while (i < 21 * 21) {
                    int pr = oy0 - 2 + r;
                    int pc = ox0 - 2 + c;
                    f2 v;
                    if (pr < 0 || pr > H + 1 || pc < 0 || pc > W + 1) {
                        v = 0.0f;
                    } else if (pr == 0 || pr == H + 1 || pc == 0 || pc == W + 1) {
                        v = 1.0f;
                    } else {
                        v = mk2(MP - pb[(pr - 1) * W + (pc - 1)],
                                MG - gb[(pr - 1) * W + (pc - 1)]);
                    }
                    win[r][c] = v;
                    i += 256; c += 4; r += 12;
                    if (c >= 21) { c -= 21; r += 1; }
                }
            }
            __syncthreads();
            NC2 ac = sweep2<23>(&win[ty][tx]);
            ssum_from_nc2<false>(ac, nullptr, nullptr, sc, junk);
            po[1] = __halves2half2(__float2half(sig_cp(ac.v.x * sc.x)),
                                   __float2half(sig_cp(ac.v.y * sc.y)));
        }
    }
}

// ---------------- dil_diff: 2 cols/thread, 3-row ring, interleaved f16 -------
// 512 blocks per level: block r -> (b = r>>6, rowgroup = r&63); tid -> column
// pair x0 = 2*tid. 4 record loads per row cover 2 output columns.
__global__ __launch_bounds__(256, 4) void dil_diff2_kernel(
    const __half* __restrict__ cp, float* __restrict__ partial) {
    const int plane_grp = blockIdx.x >> 9;  // 512 blocks per level
    const int r = blockIdx.x & 511;
    const __half* cpb = cp + (size_t)(4 * plane_grp) * NPIX;
    const int x0 = threadIdx.x << 1;
    const int y0 = (r & 63) << 3;
    const int b = r >> 6;
    const __half* pb = cpb + (size_t)b * HW * 4;

    float4 ring0[3], ring1[3];
    float s = 0.0f;
#pragma unroll
    for (int j = 0; j < 10; j++) {
        int yy = y0 - 1 + j;
        float4 a0 = make_float4(0.f, 0.f, 0.f, 0.f);
        float4 a1 = a0;
        if (yy >= 0 && yy < H) {  // wave-uniform
            const __half* row = pb + (size_t)yy * (W * 4);
            float4 f0 = h4_to_f4(*(const uint64_t*)(row + (size_t)x0 * 4));
            float4 f1 = h4_to_f4(*(const uint64_t*)(row + (size_t)(x0 + 1) * 4));
            float4 lf = make_float4(0.f, 0.f, 0.f, 0.f), rt = lf;
            if (x0 > 0)
                lf = h4_to_f4(*(const uint64_t*)(row + (size_t)(x0 - 1) * 4));
            if (x0 + 2 < W)
                rt = h4_to_f4(*(const uint64_t*)(row + (size_t)(x0 + 2) * 4));
            a0 = f4_add(f4_add(lf, f0), f1);   // (l + m) + r, bit-exact
            a1 = f4_add(f4_add(f0, f1), rt);
        }
        ring0[j % 3] = a0; ring1[j % 3] = a1;
        if (j >= 2) {
            float4 v0 = f4_add(f4_add(ring0[(j - 2) % 3], ring0[(j - 1) % 3]),
                               ring0[j % 3]);
            float4 v1 = f4_add(f4_add(ring1[(j - 2) % 3], ring1[(j - 1) % 3]),
                               ring1[j % 3]);
            float d1 = fminf(v0.x, 1.0f) - fminf(v0.y, 1.0f);
            float d2 = fminf(v0.z, 1.0f) - fminf(v0.w, 1.0f);
            s += fmaf(d1, d1, d2 * d2);
            d1 = fminf(v1.x, 1.0f) - fminf(v1.y, 1.0f);
            d2 = fminf(v1.z, 1.0f) - fminf(v1.w, 1.0f);
            s += fmaf(d1, d1, d2 * d2);
        }
    }
    s = wave_sum(s);
    __shared__ float red[4];
    int tid = threadIdx.x;
    if ((tid & 63) == 0) red[tid >> 6] = s;
    __syncthreads();
    if (tid == 0) partial[blockIdx.x] = (red[0] + red[1]) + (red[2] + red[3]);
}

// ---------------- cross-conv 4px/thread helper -------------------------------
__device__ __forceinline__ void cross4(const float* __restrict__ xp, int idx,
                                       int y, int c, float4& ctr, float t[4]) {
    const float4* v = (const float4*)(xp + idx);
    ctr = v[0];
    float4 up = (y > 0) ? *(const float4*)(xp + idx - W)
                        : make_float4(0, 0, 0, 0);
    float4 dn = (y < H - 1) ? *(const float4*)(xp + idx + W)
                            : make_float4(0, 0, 0, 0);
    float lf = (c > 0) ? xp[idx - 1] : 0.0f;
    float rt = (c < W - 4) ? xp[idx + 4] : 0.0f;
    t[0] = (up.x + dn.x) + (lf + ctr.y);
    t[1] = (up.y + dn.y) + (ctr.x + ctr.z);
    t[2] = (up.z + dn.z) + (ctr.y + ctr.w);
    t[3] = (up.w + dn.w) + (ctr.z + rt);
}

// ---------------- erosion: cross-conv max pass -> float4 partial/block -------
__global__ __launch_bounds__(256) void cross_max_both_kernel(
    const float* __restrict__ xP, const float* __restrict__ xG,
    float4* __restrict__ partial) {
    float mtP = 0, mtG = 0, mrP = 0, mrG = 0;
    for (int T = blockIdx.x * 256 + threadIdx.x; T < NPIX / 4; T += NB1 * 256) {
        int idx = T * 4;
        int i = idx & (HW - 1);
        int y = i >> 9;
        int c = i & (W - 1);
        float4 ctr;
        float t[4];
        cross4(xP, idx, y, c, ctr, t);
        mtP = fmaxf(mtP, fmaxf(fmaxf(t[0], t[1]), fmaxf(t[2], t[3])));
        mrP = fmaxf(mrP, fmaxf(fmaxf(ctr.x, ctr.y), fmaxf(ctr.z, ctr.w)));
        cross4(xG, idx, y, c, ctr, t);
        mtG = fmaxf(mtG, fmaxf(fmaxf(t[0], t[1]), fmaxf(t[2], t[3])));
        mrG = fmaxf(mrG, fmaxf(fmaxf(ctr.x, ctr.y), fmaxf(ctr.z, ctr.w)));
    }
    mtP = wave_max(mtP); mtG = wave_max(mtG);
    mrP = wave_max(mrP); mrG = wave_max(mrG);
    __shared__ float red[4][4];
    int tid = threadIdx.x;
    if ((tid & 63) == 0) {
        int w = tid >> 6;
        red[w][0] = mtP; red[w][1] = mtG; red[w][2] = mrP; red[w][3] = mrG;
    }
    __syncthreads();
    if (tid == 0) {
        float4 r;
        r.x = fmaxf(fmaxf(red[0][0], red[1][0]), fmaxf(red[2][0], red[3][0]));
        r.y = fmaxf(fmaxf(red[0][1], red[1][1]), fmaxf(red[2][1], red[3][1]));
        r.z = fmaxf(fmaxf(red[0][2], red[1][2]), fmaxf(red[2][2], red[3][2]));
        r.w = fmaxf(fmaxf(red[0][3], red[1][3]), fmaxf(red[2][3], red[3][3]));
        partial[blockIdx.x] = r;
    }
}

// ---------------- erosion: fused PM-reduce + cross conv + normalize ----------
__global__ __launch_bounds__(256) void erode_both_kernel(
    const float* __restrict__ xP, const float* __restrict__ xG,
    const float4* __restrict__ PM,
    float* __restrict__ yP, float* __restrict__ yG,
    float* ymaxP, float* ymaxG, float* rmaxP, float* rmaxG) {
    // redundant per-block PM reduce (16KB, L2-resident)
    float a = 0, bm = 0, c4 = 0, d4 = 0;
    {
        int t = threadIdx.x;
#pragma unroll
        for (int k = 0; k < NB1 / 256; k++) {
            float4 p = PM[t + k * 256];
            a = fmaxf(a, p.x); bm = fmaxf(bm, p.y);
            c4 = fmaxf(c4, p.z); d4 = fmaxf(d4, p.w);
        }
        a = wave_max(a); bm = wave_max(bm); c4 = wave_max(c4); d4 = wave_max(d4);
        __shared__ float red[4][4];
        if ((t & 63) == 0) {
            int w = t >> 6;
            red[w][0] = a; red[w][1] = bm; red[w][2] = c4; red[w][3] = d4;
        }
        __syncthreads();
        a  = fmaxf(fmaxf(red[0][0], red[1][0]), fmaxf(red[2][0], red[3][0]));
        bm = fmaxf(fmaxf(red[0][1], red[1][1]), fmaxf(red[2][1], red[3][1]));
        c4 = fmaxf(fmaxf(red[0][2], red[1][2]), fmaxf(red[2][2], red[3][2]));
        d4 = fmaxf(fmaxf(red[0][3], red[1][3]), fmaxf(red[2][3], red[3][3]));
    }
    const float tP_max = a, tG_max = bm;
    const float invP = rcpf(tP_max + 1e-8f);
    const float invG = rcpf(tG_max + 1e-8f);

    const int T = blockIdx.x * 256 + threadIdx.x;  // 2048 blocks cover NPIX/4
    if (T < NPIX / 4) {
        int idx = T * 4;
        int i = idx & (HW - 1);
        int y = i >> 9;
        int c = i & (W - 1);
        float4 ctr;
        float t[4], o[4];
        cross4(xP, idx, y, c, ctr, t);
#pragma unroll
        for (int k = 0; k < 4; k++) o[k] = sig_er(t[k] * invP);
        *(float4*)(yP + idx) = make_float4(o[0], o[1], o[2], o[3]);
        cross4(xG, idx, y, c, ctr, t);
#pragma unroll
        for (int k = 0; k < 4; k++) o[k] = sig_er(t[k] * invG);
        *(float4*)(yG + idx) = make_float4(o[0], o[1], o[2], o[3]);
    }
    if (blockIdx.x == 0 && threadIdx.x == 0) {
        *ymaxP = sig_er(tP_max * invP);
        *ymaxG = sig_er(tG_max * invG);
        *rmaxP = c4;
        *rmaxG = d4;
    }
}

// ---------------- final: sum 1536 partials, /B -------------------------------
__global__ __launch_bounds__(1024) void finalize_kernel(
    const float* __restrict__ PS, float* out) {
    int t = threadIdx.x;
    float s = PS[t] + ((t < 512) ? PS[t + 1024] : 0.0f);
    s = wave_sum(s);
    __shared__ float red[16];
    if ((t & 63) == 0) red[t >> 6] = s;
    __syncthreads();
    if (t == 0) {
        float tot = 0.0f;
#pragma unroll
        for (int i = 0; i < 16; i++) tot += red[i];
        out[0] = tot * (1.0f / (float)B);
    }
}

// ---------------- launch -----------------------------------------------------
extern "C" void kernel_launch(void* const* d_in, const int* in_sizes, int n_in,
                              void* d_out, int out_size, void* d_ws, size_t ws_size,
                              hipStream_t stream) {
    (void)in_sizes; (void)n_in; (void)out_size;
    const float* pred = (const float*)d_in[0];
    const float* gt   = (const float*)d_in[1];
    float* out = (float*)d_out;

    // ws (floats): S[64] | PM[4*NB1] | PS[3*NBD] | P1,G1,P2,G2 | CP (f16)
    // CST (72 floats) aliases the PM region (dead after erode2).
    float* S  = (float*)d_ws;
    float4* PM = (float4*)(S + 64);
    float* CST = S + 64;
    float* PS = S + 64 + 4 * NB1;
    float* P1 = PS + 3 * NBD;
    float* G1 = P1 + NPIX;
    float* P2 = G1 + NPIX;
    float* G2 = P2 + NPIX;
    __half* CP = (__half*)(G2 + NPIX);

    // merged path needs 12 f16 CP planes (48MB); fallback needs 4
    const size_t base_b = (size_t)(64 + 4 * NB1 + 3 * NBD) * 4 +
                          (size_t)4 * NPIX * 4;
    const bool merged = ws_size >= base_b + (size_t)12 * NPIX * 2;

    const dim3 b1(256), g1(NB1), gE(NPIX / 4 / 256);
    const dim3 b2(16, 16, 1);

    // erosion chain (separate dispatches = cheap barriers; R17 coop sync failed)
    cross_max_both_kernel<<<g1, b1, 0, stream>>>(pred, gt, PM);
    erode_both_kernel<<<gE, b1, 0, stream>>>(pred, gt, PM, P1, G1,
                                             S + 1, S + 4, S + 0, S + 3);
    cross_max_both_kernel<<<g1, b1, 0, stream>>>(P1, G1, PM);
    erode_both_kernel<<<gE, b1, 0, stream>>>(P1, G1, PM, P2, G2,
                                             S + 2, S + 5, S + 12, S + 13);
    setup_consts_kernel<<<1, 64, 0, stream>>>(S, CST);

    if (merged) {
        cp_main_kernel<<<dim3(GRID_X, 1, 3 * B), b2, 0, stream>>>(
            pred, gt, P1, G1, P2, G2, S, CST, 0, 0, CP);
        dil_diff2_kernel<<<dim3(3 * 512), b1, 0, stream>>>(CP, PS);
    } else {
        for (int lvl = 0; lvl < 3; lvl++) {
            cp_main_kernel<<<dim3(GRID_X, 1, B), b2, 0, stream>>>(
                pred, gt, P1, G1, P2, G2, S, CST, lvl, lvl, CP);
            dil_diff2_kernel<<<dim3(512), b1, 0, stream>>>(CP, PS + lvl * 512);
        }
    }

    finalize_kernel<<<1, 1024, 0, stream>>>(PS, out);
}

// Round 6
// 251.568 us; speedup vs baseline: 2.8058x; 1.0184x over previous
//
#include <hip/hip_runtime.h>
#include <hip/hip_fp16.h>
#include <cstdint>

// Problem constants (setup_inputs: B=8, H=W=512, num_erosions=2)
static constexpr int B = 8;
static constexpr int H = 512;
static constexpr int W = 512;
static constexpr int HW = H * W;
static constexpr int NPIX = B * HW;
static constexpr int NB1 = 1024;  // blocks for cross_max partials
static constexpr int NBD = 1024;  // legacy partial stride (finalize layout)

// cp_main tiling: interior = 16x32 tiles (2 px/thread), edge ring = 16x16
static constexpr int N_INT = 30 * 14;   // txB in [1,30], tyB in [1,14]
static constexpr int N_EDGE = 64 + 120; // 2 cols x 32 + 4 rows x 30
static constexpr int GRID_X = N_INT + N_EDGE;  // 604

// 10*log2(e): sigmoid(10*z) = 1/(1+2^(-CC*z))
static constexpr float CC = 14.4269504088896f;

// ---------------- helpers ----------------------------------------------------
// R14: interleaved CP records (WRITE 419->49MB). R15: f2 (P,G) VOP3P packing.
// R16: 2px/thread interior + hoisted consts -> 164us, VALUBusy 82%. cp is at
//   the trans-pipe roofline: 186 trans/output (1 exp + 2 rcp per mask pair,
//   provably minimal for this formulation; product-rcp overflows; wave64
//   saturation-vote never fires for K3/K4 — explains R3's failure).
// R17 FAILED: cooperative grid.sync ~100us+ each on this runtime — separate
//   dispatches ARE the cheap barrier. R18: 256us; ~45us of it is dispatch
//   gaps (8 dispatches).
// R19: cut dispatches 8->6: (1) fuse erode1+cmax2 (y into LDS w/ 2 halo rows,
//   cross(y) max in-block; removes cmax2's 32MB pass; bit-identical y);
//   (2) fold setup_consts into erode2 block-0 tail (CST moved to PS+2560,
//   out of the PM alias). PM2 partials live at CP base (dead until cp_main
//   overwrites, after erode2 consumed them).
__device__ __forceinline__ float rcpf(float x) { return __builtin_amdgcn_rcpf(x); }
__device__ __forceinline__ float exp2f_n(float x) { return __builtin_amdgcn_exp2f(x); }

typedef __attribute__((ext_vector_type(2))) float f2;

__device__ __forceinline__ f2 mk2(float a, float b) { f2 r; r.x = a; r.y = b; return r; }
__device__ __forceinline__ f2 exp2_2(f2 v) {
    f2 r; r.x = exp2f_n(v.x); r.y = exp2f_n(v.y); return r;
}
__device__ __forceinline__ f2 rcp_2(f2 v) {
    f2 r; r.x = rcpf(v.x); r.y = rcpf(v.y); return r;
}
#if defined(__has_builtin)
#if __has_builtin(__builtin_elementwise_fma)
#define FMA2(a, b, c) __builtin_elementwise_fma((a), (b), (c))
#endif
#endif
#ifndef FMA2
__device__ __forceinline__ f2 fma2_(f2 a, f2 b, f2 c) {
    f2 r; r.x = fmaf(a.x, b.x, c.x); r.y = fmaf(a.y, b.y, c.y); return r;
}
#define FMA2(a, b, c) fma2_((a), (b), (c))
#endif

__device__ __forceinline__ float sig_cp(float x) {  // sigmoid(10(x-0.5))
    return rcpf(1.0f + exp2f_n(fmaf(x, -CC, 0.5f * CC)));
}
__device__ __forceinline__ float sig_er(float r) {  // sigmoid(10(r-0.7))
    return rcpf(1.0f + exp2f_n(fmaf(r, -CC, 0.7f * CC)));
}
// Shared-exp complement pair (R12): one exp per (direct, complement) pair.
__device__ __forceinline__ void pair_term2(f2 nc, f2 negA, f2 s2m,
                                           f2& sd, f2& sc) {
    const f2 CC2 = CC;
    const f2 one2 = 1.0f;
    f2 w = exp2_2(FMA2(nc, CC2, negA));
    sd += rcp_2(FMA2(w, s2m, one2));
    sc += w * rcp_2(w + s2m);
}
// plain direct-only sigmoid (padded edge phases), f2 lanes (P, G)
__device__ __forceinline__ void end_term2(f2 nc, f2& sd) {
    const f2 CC2 = CC;
    const f2 nCC2 = -CC;
    const f2 one2 = 1.0f;
    sd += rcp_2(one2 + exp2_2(FMA2(nc, CC2, nCC2)));
}
__device__ __forceinline__ float wave_max(float m) {
#pragma unroll
    for (int o = 32; o > 0; o >>= 1) m = fmaxf(m, __shfl_down(m, o, 64));
    return m;
}
__device__ __forceinline__ float wave_sum(float s) {
#pragma unroll
    for (int o = 32; o > 0; o >>= 1) s += __shfl_down(s, o, 64);
    return s;
}

// packed 4x f16 pixel record (planes interleaved)
union H4 {
    uint64_t u;
    __half2 h2[2];
    __half h[4];
};

__device__ __forceinline__ float4 h4_to_f4(uint64_t u) {
    H4 v; v.u = u;
    float2 p0 = __half22float2(v.h2[0]);
    float2 p1 = __half22float2(v.h2[1]);
    return make_float4(p0.x, p0.y, p1.x, p1.y);
}
__device__ __forceinline__ float4 f4_add(float4 a, float4 b) {
    return make_float4(a.x + b.x, a.y + b.y, a.z + b.z, a.w + b.w);
}

// ---------------- row-sweep mask conv sums (f2: lanes = P,G) -----------------
struct NC2 {
    f2 n3[8], n4[8], n5[8], n6[7];
    f2 v;  // center value w[3][3]
};

template <int STRIDE>
__device__ __forceinline__ NC2 sweep2(const f2* rp) {
    NC2 o;
    f2 r2s, r3s, r4s;
    f2 cen0, cen1, cen2, cen3, cen4, cen5, cen6, cen7, cen8;
    {   // win row 0 = K6 row 0
        f2 c0 = rp[0], c1 = rp[1], c2 = rp[2], c3 = rp[3], c4 = rp[4], c5 = rp[5];
        f2 c45 = c4 + c5, c01 = c0 + c1;
        f2 S6 = (c01 + (c2 + c3)) + c45;
        o.n6[0] = c45; o.n6[1] = c01; o.n6[2] = S6; o.n6[3] = S6;
        o.n6[4] = S6;  o.n6[5] = S6;  o.n6[6] = S6;
    }
    rp += STRIDE;
    {   // win row 1 = K6 r1, K5 r0, K4 r0
        f2 c0 = rp[0], c1 = rp[1], c2 = rp[2], c3 = rp[3], c4 = rp[4], c5 = rp[5];
        f2 c45 = c4 + c5, c12 = c1 + c2, c34 = c3 + c4;
        f2 S4 = c12 + c34, S5 = S4 + c5;
        f2 c15 = c1 + c5, c05 = c0 + c5, c14 = c1 + c4;
        o.n6[0] += c5;  o.n6[1] += c0;  o.n6[2] += c05; o.n6[3] += c05;
        o.n6[4] += c0;  o.n6[5] += c5;  o.n6[6] += c05;
        o.n5[0] = c45; o.n5[1] = c12; o.n5[2] = S5; o.n5[3] = S5;
        o.n5[4] = S5;  o.n5[5] = S5;  o.n5[6] = S5; o.n5[7] = c15;
        o.n4[0] = c34; o.n4[1] = c12; o.n4[2] = S4; o.n4[3] = S4;
        o.n4[4] = c14; o.n4[5] = S4;  o.n4[6] = S4; o.n4[7] = S4;
    }
    rp += STRIDE;
    {   // win row 2 = K6 r2, K5 r1, K4 r1, K3 r0
        f2 c0 = rp[0], c1 = rp[1], c2 = rp[2], c3 = rp[3], c4 = rp[4], c5 = rp[5];
        f2 c05 = c0 + c5, c15 = c1 + c5, c14 = c1 + c4;
        r2s = (c2 + c3) + c4;
        cen0 = c2; cen1 = c3; cen2 = c4;
        o.n6[0] += c5;  o.n6[1] += c0;  o.n6[2] += c0;  o.n6[3] += c5;
        o.n6[4] += c0;  o.n6[5] += c5;  o.n6[6] += c05;
        o.n5[0] += c5;  o.n5[1] += c1;  o.n5[2] += c15; o.n5[3] += c15;
        o.n5[4] += c1;  o.n5[5] += c5;  o.n5[6] += c15; o.n5[7] += c15;
        o.n4[0] += c4;  o.n4[1] += c1;  o.n4[2] += c14; o.n4[3] += c14;
        o.n4[4] += c14; o.n4[5] += c4;  o.n4[6] += c14; o.n4[7] += c1;
    }
    rp += STRIDE;
    {   // win row 3 = K6 r3, K5 r2, K4 r2, K3 r1 (center row)
        f2 c0 = rp[0], c1 = rp[1], c2 = rp[2], c3 = rp[3], c4 = rp[4], c5 = rp[5];
        f2 c05 = c0 + c5, c15 = c1 + c5, c14 = c1 + c4;
        r3s = (c2 + c3) + c4;
        cen3 = c2; cen4 = c3; cen5 = c4;
        o.v = c3;
        o.n6[0] += c5;  o.n6[1] += c0;  o.n6[2] += c0;  o.n6[3] += c5;
        o.n6[4] += c0;  o.n6[5] += c5;  o.n6[6] += c05;
        o.n5[0] += c5;  o.n5[1] += c1;  o.n5[2] += c1;  o.n5[3] += c5;
        o.n5[4] += c1;  o.n5[5] += c5;  o.n5[6] += c15; o.n5[7] += c15;
        o.n4[0] += c14; o.n4[1] += c14; o.n4[2] += c4;  o.n4[3] += c1;
        o.n4[4] += c14; o.n4[5] += c4;  o.n4[6] += c14; o.n4[7] += c1;
    }
    rp += STRIDE;
    {   // win row 4 = K6 r4, K5 r3, K4 r3, K3 r2
        f2 c0 = rp[0], c1 = rp[1], c2 = rp[2], c3 = rp[3], c4 = rp[4], c5 = rp[5];
        f2 c05 = c0 + c5, c15 = c1 + c5, c12 = c1 + c2, c34 = c3 + c4;
        f2 S4 = c12 + c34, c14 = c1 + c4;
        r4s = (c2 + c3) + c4;
        cen6 = c2; cen7 = c3; cen8 = c4;
        o.n6[0] += c05; o.n6[1] += c05; o.n6[2] += c0;  o.n6[3] += c5;
        o.n6[4] += c0;  o.n6[5] += c5;  o.n6[6] += c05;
        o.n5[0] += c15; o.n5[1] += c15; o.n5[2] += c1;  o.n5[3] += c5;
        o.n5[4] += c1;  o.n5[5] += c5;  o.n5[6] += c15; o.n5[7] += c15;
        o.n4[0] += S4;  o.n4[1] += S4;  o.n4[2] += c34; o.n4[3] += c12;
        o.n4[4] += S4;  o.n4[5] += S4;  o.n4[6] += c14; o.n4[7] += S4;
    }
    rp += STRIDE;
    {   // win row 5 = K6 r5, K5 r4
        f2 c0 = rp[0], c1 = rp[1], c2 = rp[2], c3 = rp[3], c4 = rp[4], c5 = rp[5];
        f2 c45 = c4 + c5, c12 = c1 + c2;
        f2 t = c3 + c45, S5 = c12 + t, S6 = S5 + c0;
        f2 c01 = c0 + c1, c05 = c0 + c5, c15 = c1 + c5;
        o.n6[0] += S6;  o.n6[1] += S6;  o.n6[2] += c01; o.n6[3] += c45;
        o.n6[4] += S6;  o.n6[5] += S6;  o.n6[6] += c05;
        o.n5[0] += S5;  o.n5[1] += S5;  o.n5[2] += c12; o.n5[3] += c45;
        o.n5[4] += S5;  o.n5[5] += S5;  o.n5[6] += c15; o.n5[7] += S5;
    }
    // K3: all 8 masks = S33 - center - one distinct cell
    f2 S33 = (r2s + r3s) + r4s;
    f2 T = S33 - cen4;
    o.n3[0] = T - cen3; o.n3[1] = T - cen7; o.n3[2] = T - cen5; o.n3[3] = T - cen1;
    o.n3[4] = T - cen0; o.n3[5] = T - cen6; o.n3[6] = T - cen8; o.n3[7] = T - cen2;
    return o;
}

// class index per mask into per-class constants; counts {7,9,10,11,13,16}
__constant__ __device__ const int CI4[8] = {1, 1, 1, 1, 2, 2, 2, 2};
__constant__ __device__ const int CI5[8] = {3, 3, 3, 3, 4, 4, 4, 4};
__constant__ __device__ const int CI6[7] = {4, 4, 4, 4, 5, 5, 5};

template <bool PAIR>
__device__ __forceinline__ void ssum_from_nc2(const NC2& a, const f2* negA,
                                              const f2* s2m, f2& sD, f2& sC) {
    f2 sd = 0.0f, sc = 0.0f;
#pragma unroll
    for (int k = 0; k < 8; k++) {
        if constexpr (PAIR) pair_term2(a.n3[k], negA[0], s2m[0], sd, sc);
        else end_term2(a.n3[k], sd);
    }
#pragma unroll
    for (int k = 0; k < 8; k++) {
        if constexpr (PAIR) pair_term2(a.n4[k], negA[CI4[k]], s2m[CI4[k]], sd, sc);
        else end_term2(a.n4[k], sd);
    }
#pragma unroll
    for (int k = 0; k < 8; k++) {
        if constexpr (PAIR) pair_term2(a.n5[k], negA[CI5[k]], s2m[CI5[k]], sd, sc);
        else end_term2(a.n5[k], sd);
    }
#pragma unroll
    for (int k = 0; k < 7; k++) {
        if constexpr (PAIR) pair_term2(a.n6[k], negA[CI6[k]], s2m[CI6[k]], sd, sc);
        else end_term2(a.n6[k], sd);
    }
    sD = sd;
    sC = sc;
}

// ---------------- cp_main: interior 2px/thread + edge ring -------------------
__global__ __launch_bounds__(256, 4) void cp_main_kernel(
    const float* __restrict__ x0P, const float* __restrict__ x0G,
    const float* __restrict__ x1P, const float* __restrict__ x1G,
    const float* __restrict__ x2P, const float* __restrict__ x2G,
    const float* __restrict__ S, const float* __restrict__ CST,
    int lvl_base, int plane_lvl0, __half* __restrict__ cp) {
    __shared__ f2 win[37][23];
    const int lvl = lvl_base + (blockIdx.z >> 3);
    const int b = blockIdx.z & 7;
    const float* xP = (lvl == 0) ? x0P : (lvl == 1) ? x1P : x2P;
    const float* xG = (lvl == 0) ? x0G : (lvl == 1) ? x1G : x2G;
    const float MP = S[lvl], MG = S[3 + lvl];
    __half* cpb = cp + (size_t)(4 * (lvl - plane_lvl0)) * NPIX;
    const int tid = threadIdx.y * 16 + threadIdx.x;
    const int ty = threadIdx.y, tx = threadIdx.x;
    const f2* cbase = (const f2*)(CST + lvl * 24);

    if (blockIdx.x < N_INT) {
        const int txB = 1 + (int)blockIdx.x % 30;
        const int tyB = 1 + (int)blockIdx.x / 30;
        const int ox0 = txB * 16, oy0 = tyB * 32;
        const float* pb = xP + b * HW + (oy0 - 3) * W + (ox0 - 3);
        const float* gb = xG + b * HW + (oy0 - 3) * W + (ox0 - 3);
        {   // 37x21 fill, strength-reduced indexing (256 = 12*21+4)
            int i = tid, r = tid / 21, c = tid - (tid / 21) * 21;
            while (i < 37 * 21) {
                win[r][c] = mk2(pb[r * W + c], gb[r * W + c]);
                i += 256; c += 4; r += 12;
                if (c >= 21) { c -= 21; r += 1; }
            }
        }
        __syncthreads();
        f2 negA[6], s2m[6];
#pragma unroll
        for (int c = 0; c < 6; c++) { negA[c] = cbase[c]; s2m[c] = cbase[6 + c]; }
        int o = b * HW + (oy0 + ty) * W + (ox0 + tx);
        {
            f2 sd, sc;
            NC2 a = sweep2<23>(&win[ty][tx]);
            ssum_from_nc2<true>(a, negA, s2m, sd, sc);
            H4 v;
            v.h[0] = __float2half(sig_cp(a.v.x * sd.x));
            v.h[1] = __float2half(sig_cp(a.v.y * sd.y));
            v.h[2] = __float2half(sig_cp((MP - a.v.x) * sc.x));
            v.h[3] = __float2half(sig_cp((MG - a.v.y) * sc.y));
            *(uint64_t*)(cpb + (size_t)o * 4) = v.u;
        }
        o += 16 * W;
        {
            f2 sd, sc;
            NC2 a = sweep2<23>(&win[ty + 16][tx]);
            ssum_from_nc2<true>(a, negA, s2m, sd, sc);
            H4 v;
            v.h[0] = __float2half(sig_cp(a.v.x * sd.x));
            v.h[1] = __float2half(sig_cp(a.v.y * sd.y));
            v.h[2] = __float2half(sig_cp((MP - a.v.x) * sc.x));
            v.h[3] = __float2half(sig_cp((MG - a.v.y) * sc.y));
            *(uint64_t*)(cpb + (size_t)o * 4) = v.u;
        }
    } else {
        const int e = (int)blockIdx.x - N_INT;
        int tx16, ty16;
        if (e < 64) {
            ty16 = e >> 1;
            tx16 = (e & 1) ? 31 : 0;
        } else {
            int e2 = e - 64;
            int r = e2 / 30;
            ty16 = (r == 0) ? 0 : (r == 1) ? 1 : (r == 2) ? 30 : 31;
            tx16 = 1 + e2 % 30;
        }
        const int ox0 = tx16 * 16, oy0 = ty16 * 16;
        const int o = b * HW + (oy0 + ty) * W + (ox0 + tx);
        const bool fastw = (tx16 >= 1) & (tx16 <= 30) & (ty16 >= 1) & (ty16 <= 30);
        if (fastw) {
            const float* pb = xP + b * HW + (oy0 - 3) * W + (ox0 - 3);
            const float* gb = xG + b * HW + (oy0 - 3) * W + (ox0 - 3);
            {
                int i = tid, r = tid / 21, c = tid - (tid / 21) * 21;
                while (i < 21 * 21) {
                    win[r][c] = mk2(pb[r * W + c], gb[r * W + c]);
                    i += 256; c += 4; r += 12;
                    if (c >= 21) { c -= 21; r += 1; }
                }
            }
            __syncthreads();
            f2 negA[6], s2m[6], sd, sc;
#pragma unroll
            for (int c = 0; c < 6; c++) { negA[c] = cbase[c]; s2m[c] = cbase[6 + c]; }
            NC2 a = sweep2<23>(&win[ty][tx]);
            ssum_from_nc2<true>(a, negA, s2m, sd, sc);
            H4 v;
            v.h[0] = __float2half(sig_cp(a.v.x * sd.x));
            v.h[1] = __float2half(sig_cp(a.v.y * sd.y));
            v.h[2] = __float2half(sig_cp((MP - a.v.x) * sc.x));
            v.h[3] = __float2half(sig_cp((MG - a.v.y) * sc.y));
            *(uint64_t*)(cpb + (size_t)o * 4) = v.u;
        } else {
            const float* pb = xP + b * HW;
            const float* gb = xG + b * HW;
            // phase A: direct planes
            {
                int i = tid, r = tid / 21, c = tid - (tid / 21) * 21;
                while (i < 21 * 21) {
                    int pr = oy0 - 2 + r;  // padded coords (0..513 valid)
                    int pc = ox0 - 2 + c;
                    f2 v;
                    if (pr < 0 || pr > H + 1 || pc < 0 || pc > W + 1) {
                        v = 0.0f;  // conv zero-pad
                    } else if (pr == 0 || pr == H + 1 || pc == 0 || pc == W + 1) {
                        v = 1.0f;  // image 1-pad
                    } else {
                        v = mk2(pb[(pr - 1) * W + (pc - 1)], gb[(pr - 1) * W + (pc - 1)]);
                    }
                    win[r][c] = v;
                    i += 256; c += 4; r += 12;
                    if (c >= 21) { c -= 21; r += 1; }
                }
            }
            __syncthreads();
            f2 sd, sc, junk;
            NC2 a = sweep2<23>(&win[ty][tx]);
            ssum_from_nc2<false>(a, nullptr, nullptr, sd, junk);
            f2 vD = a.v;
            __half2* po = (__half2*)(cpb + (size_t)o * 4);
            po[0] = __halves2half2(__float2half(sig_cp(vD.x * sd.x)),
                                   __float2half(sig_cp(vD.y * sd.y)));
            __syncthreads();  // all reads of direct planes done
            // phase B: complement planes
            {
                int i = tid, r = tid / 21, c = tid - (tid / 21) * 21;
                while (i < 21 * 21) {
                    int pr = oy0 - 2 + r;
                    int pc = ox0 - 2 + c;
                    f2 v;
                    if (pr < 0 || pr > H + 1 || pc < 0 || pc > W + 1) {
                        v = 0.0f;
                    } else if (pr == 0 || pr == H + 1 || pc == 0 || pc == W + 1) {
                        v = 1.0f;
                    } else {
                        v = mk2(MP - pb[(pr - 1) * W + (pc - 1)],
                                MG - gb[(pr - 1) * W + (pc - 1)]);
                    }
                    win[r][c] = v;
                    i += 256; c += 4; r += 12;
                    if (c >= 21) { c -= 21; r += 1; }
                }
            }
            __syncthreads();
            NC2 ac = sweep2<23>(&win[ty][tx]);
            ssum_from_nc2<false>(ac, nullptr, nullptr, sc, junk);
            po[1] = __halves2half2(__float2half(sig_cp(ac.v.x * sc.x)),
                                   __float2half(sig_cp(ac.v.y * sc.y)));
        }
    }
}

// ---------------- dil_diff: 2 cols/thread, 3-row ring, interleaved f16 -------
__global__ __launch_bounds__(256, 4) void dil_diff2_kernel(
    const __half* __restrict__ cp, float* __restrict__ partial) {
    const int plane_grp = blockIdx.x >> 9;  // 512 blocks per level
    const int r = blockIdx.x & 511;
    const __half* cpb = cp + (size_t)(4 * plane_grp) * NPIX;
    const int x0 = threadIdx.x << 1;
    const int y0 = (r & 63) << 3;
    const int b = r >> 6;
    const __half* pb = cpb + (size_t)b * HW * 4;

    float4 ring0[3], ring1[3];
    float s = 0.0f;
#pragma unroll
    for (int j = 0; j < 10; j++) {
        int yy = y0 - 1 + j;
        float4 a0 = make_float4(0.f, 0.f, 0.f, 0.f);
        float4 a1 = a0;
        if (yy >= 0 && yy < H) {  // wave-uniform
            const __half* row = pb + (size_t)yy * (W * 4);
            float4 f0 = h4_to_f4(*(const uint64_t*)(row + (size_t)x0 * 4));
            float4 f1 = h4_to_f4(*(const uint64_t*)(row + (size_t)(x0 + 1) * 4));
            float4 lf = make_float4(0.f, 0.f, 0.f, 0.f), rt = lf;
            if (x0 > 0)
                lf = h4_to_f4(*(const uint64_t*)(row + (size_t)(x0 - 1) * 4));
            if (x0 + 2 < W)
                rt = h4_to_f4(*(const uint64_t*)(row + (size_t)(x0 + 2) * 4));
            a0 = f4_add(f4_add(lf, f0), f1);   // (l + m) + r, bit-exact
            a1 = f4_add(f4_add(f0, f1), rt);
        }
        ring0[j % 3] = a0; ring1[j % 3] = a1;
        if (j >= 2) {
            float4 v0 = f4_add(f4_add(ring0[(j - 2) % 3], ring0[(j - 1) % 3]),
                               ring0[j % 3]);
            float4 v1 = f4_add(f4_add(ring1[(j - 2) % 3], ring1[(j - 1) % 3]),
                               ring1[j % 3]);
            float d1 = fminf(v0.x, 1.0f) - fminf(v0.y, 1.0f);
            float d2 = fminf(v0.z, 1.0f) - fminf(v0.w, 1.0f);
            s += fmaf(d1, d1, d2 * d2);
            d1 = fminf(v1.x, 1.0f) - fminf(v1.y, 1.0f);
            d2 = fminf(v1.z, 1.0f) - fminf(v1.w, 1.0f);
            s += fmaf(d1, d1, d2 * d2);
        }
    }
    s = wave_sum(s);
    __shared__ float red[4];
    int tid = threadIdx.x;
    if ((tid & 63) == 0) red[tid >> 6] = s;
    __syncthreads();
    if (tid == 0) partial[blockIdx.x] = (red[0] + red[1]) + (red[2] + red[3]);
}

// ---------------- cross-conv 4px/thread helpers ------------------------------
__device__ __forceinline__ void cross4(const float* __restrict__ xp, int idx,
                                       int y, int c, float4& ctr, float t[4]) {
    const float4* v = (const float4*)(xp + idx);
    ctr = v[0];
    float4 up = (y > 0) ? *(const float4*)(xp + idx - W)
                        : make_float4(0, 0, 0, 0);
    float4 dn = (y < H - 1) ? *(const float4*)(xp + idx + W)
                            : make_float4(0, 0, 0, 0);
    float lf = (c > 0) ? xp[idx - 1] : 0.0f;
    float rt = (c < W - 4) ? xp[idx + 4] : 0.0f;
    t[0] = (up.x + dn.x) + (lf + ctr.y);
    t[1] = (up.y + dn.y) + (ctr.x + ctr.z);
    t[2] = (up.z + dn.z) + (ctr.y + ctr.w);
    t[3] = (up.w + dn.w) + (ctr.z + rt);
}

// cross over LDS rows (halo rows pre-zeroed, so no row conditionals)
__device__ __forceinline__ void cross_lds(const float* rm1, const float* r0,
                                          const float* rp1, int col,
                                          float4& ctr, float t[4]) {
    ctr = *(const float4*)(r0 + col);
    float4 up = *(const float4*)(rm1 + col);
    float4 dn = *(const float4*)(rp1 + col);
    float lf = (col > 0) ? r0[col - 1] : 0.0f;
    float rt = (col < W - 4) ? r0[col + 4] : 0.0f;
    t[0] = (up.x + dn.x) + (lf + ctr.y);
    t[1] = (up.y + dn.y) + (ctr.x + ctr.z);
    t[2] = (up.z + dn.z) + (ctr.y + ctr.w);
    t[3] = (up.w + dn.w) + (ctr.z + rt);
}

// ---------------- erosion: cross-conv max pass -> float4 partial/block -------
__global__ __launch_bounds__(256) void cross_max_both_kernel(
    const float* __restrict__ xP, const float* __restrict__ xG,
    float4* __restrict__ partial) {
    float mtP = 0, mtG = 0, mrP = 0, mrG = 0;
    for (int T = blockIdx.x * 256 + threadIdx.x; T < NPIX / 4; T += NB1 * 256) {
        int idx = T * 4;
        int i = idx & (HW - 1);
        int y = i >> 9;
        int c = i & (W - 1);
        float4 ctr;
        float t[4];
        cross4(xP, idx, y, c, ctr, t);
        mtP = fmaxf(mtP, fmaxf(fmaxf(t[0], t[1]), fmaxf(t[2], t[3])));
        mrP = fmaxf(mrP, fmaxf(fmaxf(ctr.x, ctr.y), fmaxf(ctr.z, ctr.w)));
        cross4(xG, idx, y, c, ctr, t);
        mtG = fmaxf(mtG, fmaxf(fmaxf(t[0], t[1]), fmaxf(t[2], t[3])));
        mrG = fmaxf(mrG, fmaxf(fmaxf(ctr.x, ctr.y), fmaxf(ctr.z, ctr.w)));
    }
    mtP = wave_max(mtP); mtG = wave_max(mtG);
    mrP = wave_max(mrP); mrG = wave_max(mrG);
    __shared__ float red[4][4];
    int tid = threadIdx.x;
    if ((tid & 63) == 0) {
        int w = tid >> 6;
        red[w][0] = mtP; red[w][1] = mtG; red[w][2] = mrP; red[w][3] = mrG;
    }
    __syncthreads();
    if (tid == 0) {
        float4 r;
        r.x = fmaxf(fmaxf(red[0][0], red[1][0]), fmaxf(red[2][0], red[3][0]));
        r.y = fmaxf(fmaxf(red[0][1], red[1][1]), fmaxf(red[2][1], red[3][1]));
        r.z = fmaxf(fmaxf(red[0][2], red[1][2]), fmaxf(red[2][2], red[3][2]));
        r.w = fmaxf(fmaxf(red[0][3], red[1][3]), fmaxf(red[2][3], red[3][3]));
        partial[blockIdx.x] = r;
    }
}

// ---------------- fused erode + next cross-max -------------------------------
// 1024 blocks: b = bid>>7, y0 = (bid&127)*4. Computes y = sig_er(cross(x)*inv)
// for rows y0-1..y0+4 into LDS (bit-identical ops to erode_both); writes owned
// rows y0..y0+3 to global; then cross(y) block-max -> PMo[bid].
__global__ __launch_bounds__(256) void erode_cmax_kernel(
    const float* __restrict__ xP, const float* __restrict__ xG,
    const float4* __restrict__ PM1,
    float* __restrict__ yP, float* __restrict__ yG,
    float4* __restrict__ PMo, float* __restrict__ S) {
    __shared__ float lyP[6][W], lyG[6][W];
    __shared__ float red[4][4];
    const int tid = threadIdx.x;
    const int b = blockIdx.x >> 7;
    const int y0 = ((int)blockIdx.x & 127) << 2;

    // redundant PM1 reduce (16KB, L2-resident)
    float a = 0, bm = 0, c4 = 0, d4 = 0;
#pragma unroll
    for (int k = 0; k < NB1 / 256; k++) {
        float4 p = PM1[tid + k * 256];
        a = fmaxf(a, p.x); bm = fmaxf(bm, p.y);
        c4 = fmaxf(c4, p.z); d4 = fmaxf(d4, p.w);
    }
    a = wave_max(a); bm = wave_max(bm); c4 = wave_max(c4); d4 = wave_max(d4);
    if ((tid & 63) == 0) {
        int w = tid >> 6;
        red[w][0] = a; red[w][1] = bm; red[w][2] = c4; red[w][3] = d4;
    }
    __syncthreads();
    a  = fmaxf(fmaxf(red[0][0], red[1][0]), fmaxf(red[2][0], red[3][0]));
    bm = fmaxf(fmaxf(red[0][1], red[1][1]), fmaxf(red[2][1], red[3][1]));
    c4 = fmaxf(fmaxf(red[0][2], red[1][2]), fmaxf(red[2][2], red[3][2]));
    d4 = fmaxf(fmaxf(red[0][3], red[1][3]), fmaxf(red[2][3], red[3][3]));
    const float invP = rcpf(a + 1e-8f);
    const float invG = rcpf(bm + 1e-8f);

    // y rows y0-1 .. y0+4 (6 rows x 128 chunks); halo rows OOB -> zeros
    for (int t = tid; t < 6 * 128; t += 256) {
        int ri = t >> 7;
        int col = (t & 127) << 2;
        int yy = y0 - 1 + ri;
        float4 oP = make_float4(0.f, 0.f, 0.f, 0.f), oG = oP;
        if (yy >= 0 && yy < H) {
            int idx = b * HW + yy * W + col;
            float4 ctr; float tv[4];
            cross4(xP, idx, yy, col, ctr, tv);
            oP = make_float4(sig_er(tv[0] * invP), sig_er(tv[1] * invP),
                             sig_er(tv[2] * invP), sig_er(tv[3] * invP));
            cross4(xG, idx, yy, col, ctr, tv);
            oG = make_float4(sig_er(tv[0] * invG), sig_er(tv[1] * invG),
                             sig_er(tv[2] * invG), sig_er(tv[3] * invG));
            if (ri >= 1 && ri <= 4) {  // owned rows
                *(float4*)(yP + idx) = oP;
                *(float4*)(yG + idx) = oG;
            }
        }
        *(float4*)(&lyP[ri][col]) = oP;
        *(float4*)(&lyG[ri][col]) = oG;
    }
    __syncthreads();

    // cross(y) max over owned rows (4 x 128 chunks)
    float mtP = 0, mtG = 0, mrP = 0, mrG = 0;
    for (int t = tid; t < 4 * 128; t += 256) {
        int rj = 1 + (t >> 7);
        int col = (t & 127) << 2;
        float4 ctr; float tv[4];
        cross_lds(lyP[rj - 1], lyP[rj], lyP[rj + 1], col, ctr, tv);
        mtP = fmaxf(mtP, fmaxf(fmaxf(tv[0], tv[1]), fmaxf(tv[2], tv[3])));
        mrP = fmaxf(mrP, fmaxf(fmaxf(ctr.x, ctr.y), fmaxf(ctr.z, ctr.w)));
        cross_lds(lyG[rj - 1], lyG[rj], lyG[rj + 1], col, ctr, tv);
        mtG = fmaxf(mtG, fmaxf(fmaxf(tv[0], tv[1]), fmaxf(tv[2], tv[3])));
        mrG = fmaxf(mrG, fmaxf(fmaxf(ctr.x, ctr.y), fmaxf(ctr.z, ctr.w)));
    }
    mtP = wave_max(mtP); mtG = wave_max(mtG);
    mrP = wave_max(mrP); mrG = wave_max(mrG);
    __syncthreads();  // red[] reuse
    if ((tid & 63) == 0) {
        int w = tid >> 6;
        red[w][0] = mtP; red[w][1] = mtG; red[w][2] = mrP; red[w][3] = mrG;
    }
    __syncthreads();
    if (tid == 0) {
        float4 r;
        r.x = fmaxf(fmaxf(red[0][0], red[1][0]), fmaxf(red[2][0], red[3][0]));
        r.y = fmaxf(fmaxf(red[0][1], red[1][1]), fmaxf(red[2][1], red[3][1]));
        r.z = fmaxf(fmaxf(red[0][2], red[1][2]), fmaxf(red[2][2], red[3][2]));
        r.w = fmaxf(fmaxf(red[0][3], red[1][3]), fmaxf(red[2][3], red[3][3]));
        PMo[blockIdx.x] = r;
        if (blockIdx.x == 0) {
            S[1] = sig_er(a * invP);   // ymax P1
            S[4] = sig_er(bm * invG);  // ymax G1
            S[0] = c4;                 // rmax pred
            S[3] = d4;                 // rmax gt
        }
    }
}

// ---------------- erosion: fused PM-reduce + cross conv + normalize + CST ----
__global__ __launch_bounds__(256) void erode_both_kernel(
    const float* __restrict__ xP, const float* __restrict__ xG,
    const float4* __restrict__ PM,
    float* __restrict__ yP, float* __restrict__ yG,
    float* ymaxP, float* ymaxG, float* rmaxP, float* rmaxG,
    const float* __restrict__ Sg, float* __restrict__ CST) {
    // redundant per-block PM reduce (16KB, L2-resident)
    float a = 0, bm = 0, c4 = 0, d4 = 0;
    {
        int t = threadIdx.x;
#pragma unroll
        for (int k = 0; k < NB1 / 256; k++) {
            float4 p = PM[t + k * 256];
            a = fmaxf(a, p.x); bm = fmaxf(bm, p.y);
            c4 = fmaxf(c4, p.z); d4 = fmaxf(d4, p.w);
        }
        a = wave_max(a); bm = wave_max(bm); c4 = wave_max(c4); d4 = wave_max(d4);
        __shared__ float red[4][4];
        if ((t & 63) == 0) {
            int w = t >> 6;
            red[w][0] = a; red[w][1] = bm; red[w][2] = c4; red[w][3] = d4;
        }
        __syncthreads();
        a  = fmaxf(fmaxf(red[0][0], red[1][0]), fmaxf(red[2][0], red[3][0]));
        bm = fmaxf(fmaxf(red[0][1], red[1][1]), fmaxf(red[2][1], red[3][1]));
        c4 = fmaxf(fmaxf(red[0][2], red[1][2]), fmaxf(red[2][2], red[3][2]));
        d4 = fmaxf(fmaxf(red[0][3], red[1][3]), fmaxf(red[2][3], red[3][3]));
    }
    const float tP_max = a, tG_max = bm;
    const float invP = rcpf(tP_max + 1e-8f);
    const float invG = rcpf(tG_max + 1e-8f);

    const int T = blockIdx.x * 256 + threadIdx.x;  // 2048 blocks cover NPIX/4
    if (T < NPIX / 4) {
        int idx = T * 4;
        int i = idx & (HW - 1);
        int y = i >> 9;
        int c = i & (W - 1);
        float4 ctr;
        float t[4], o[4];
        cross4(xP, idx, y, c, ctr, t);
#pragma unroll
        for (int k = 0; k < 4; k++) o[k] = sig_er(t[k] * invP);
        *(float4*)(yP + idx) = make_float4(o[0], o[1], o[2], o[3]);
        cross4(xG, idx, y, c, ctr, t);
#pragma unroll
        for (int k = 0; k < 4; k++) o[k] = sig_er(t[k] * invG);
        *(float4*)(yG + idx) = make_float4(o[0], o[1], o[2], o[3]);
    }
    if (blockIdx.x == 0) {
        if (threadIdx.x == 0) {
            *ymaxP = sig_er(tP_max * invP);
            *ymaxG = sig_er(tG_max * invG);
            *rmaxP = c4;
            *rmaxG = d4;
        }
        // folded setup_consts: CST[lvl*24 + cls*2 + img] = negA; +12 -> s2m.
        if (threadIdx.x < 36) {
            int t = threadIdx.x;
            int lvl = t / 12, rem = t % 12, cls = rem >> 1, img = rem & 1;
            const float cntf[6] = {7.0f, 9.0f, 10.0f, 11.0f, 13.0f, 16.0f};
            float M;
            if (lvl == 2)
                M = img ? sig_er(tG_max * invG) : sig_er(tP_max * invP);
            else
                M = Sg[lvl + 3 * img];
            float cm = fmaf(cntf[cls] * M, CC, -CC);
            float m = 0.5f * (cm - CC);
            CST[lvl * 24 + cls * 2 + img] = -(CC + m);
            CST[lvl * 24 + 12 + cls * 2 + img] = exp2f_n(m);
        }
    }
}

// ---------------- final: sum 1536 partials, /B -------------------------------
__global__ __launch_bounds__(1024) void finalize_kernel(
    const float* __restrict__ PS, float* out) {
    int t = threadIdx.x;
    float s = PS[t] + ((t < 512) ? PS[t + 1024] : 0.0f);
    s = wave_sum(s);
    __shared__ float red[16];
    if ((t & 63) == 0) red[t >> 6] = s;
    __syncthreads();
    if (t == 0) {
        float tot = 0.0f;
#pragma unroll
        for (int i = 0; i < 16; i++) tot += red[i];
        out[0] = tot * (1.0f / (float)B);
    }
}

// ---------------- launch -----------------------------------------------------
extern "C" void kernel_launch(void* const* d_in, const int* in_sizes, int n_in,
                              void* d_out, int out_size, void* d_ws, size_t ws_size,
                              hipStream_t stream) {
    (void)in_sizes; (void)n_in; (void)out_size;
    const float* pred = (const float*)d_in[0];
    const float* gt   = (const float*)d_in[1];
    float* out = (float*)d_out;

    // ws (floats): S[64] | PM[4*NB1] | PS[3*NBD] | P1,G1,P2,G2 | CP (f16)
    // CST at PS+2560 (72 floats, outside dil's PS[0..1536) use).
    // PM2 partials (1024 float4) alias the CP base: erode_cmax writes ->
    // erode2 reads -> cp_main overwrites (stream-ordered, safe; 16B-aligned).
    float* S  = (float*)d_ws;
    float4* PM = (float4*)(S + 64);
    float* PS = S + 64 + 4 * NB1;
    float* CST = PS + 2560;
    float* P1 = PS + 3 * NBD;
    float* G1 = P1 + NPIX;
    float* P2 = G1 + NPIX;
    float* G2 = P2 + NPIX;
    __half* CP = (__half*)(G2 + NPIX);
    float4* PM2 = (float4*)CP;

    // merged path needs 12 f16 CP planes (48MB); fallback needs 4
    const size_t base_b = (size_t)(64 + 4 * NB1 + 3 * NBD) * 4 +
                          (size_t)4 * NPIX * 4;
    const bool merged = ws_size >= base_b + (size_t)12 * NPIX * 2;

    const dim3 b1(256), g1(NB1), gE(NPIX / 4 / 256);
    const dim3 b2(16, 16, 1);

    // erosion chain: cmax1 -> fused(erode1+cmax2) -> erode2(+CST fold)
    cross_max_both_kernel<<<g1, b1, 0, stream>>>(pred, gt, PM);
    erode_cmax_kernel<<<dim3(NB1), b1, 0, stream>>>(pred, gt, PM, P1, G1,
                                                    PM2, S);
    erode_both_kernel<<<gE, b1, 0, stream>>>(P1, G1, PM2, P2, G2,
                                             S + 2, S + 5, S + 12, S + 13,
                                             S, CST);

    if (merged) {
        cp_main_kernel<<<dim3(GRID_X, 1, 3 * B), b2, 0, stream>>>(
            pred, gt, P1, G1, P2, G2, S, CST, 0, 0, CP);
        dil_diff2_kernel<<<dim3(3 * 512), b1, 0, stream>>>(CP, PS);
    } else {
        for (int lvl = 0; lvl < 3; lvl++) {
            cp_main_kernel<<<dim3(GRID_X, 1, B), b2, 0, stream>>>(
                pred, gt, P1, G1, P2, G2, S, CST, lvl, lvl, CP);
            dil_diff2_kernel<<<dim3(512), b1, 0, stream>>>(CP, PS + lvl * 512);
        }
    }

    finalize_kernel<<<1, 1024, 0, stream>>>(PS, out);
}